// Round 1
// baseline (369.040 us; speedup 1.0000x reference)
//
#include <hip/hip_runtime.h>
#include <math.h>

#define NA   4096
#define DAq  128
#define DMc  512
#define HH   4
#define DHh  32
#define DFf  512
#define PPp  32768
#define WIN  16
#define BAND 33

__device__ __forceinline__ float sigmoidf_(float x) { return 1.0f / (1.0f + __expf(-x)); }

// ---------------------------------------------------------------------------
// Pair-bias scatter into banded buffer band[i][h][jo], jo = j-i+16
// ---------------------------------------------------------------------------
__global__ __launch_bounds__(256) void k_scatter(
    const float* __restrict__ p_lm, const float* __restrict__ pair_w,
    const float* __restrict__ pair_b, const int* __restrict__ idx,
    float* __restrict__ band)
{
    int p = blockIdx.x * 256 + threadIdx.x;
    if (p >= PPp) return;
    int i = idx[2 * p], j = idx[2 * p + 1];
    int d = j - i + WIN;
    if (d < 0 || d > 2 * WIN) return;
    float v0 = pair_b[0], v1 = pair_b[1], v2 = pair_b[2], v3 = pair_b[3];
    #pragma unroll
    for (int k = 0; k < 16; ++k) {
        float a = p_lm[p * 16 + k];
        v0 = fmaf(a, pair_w[k * 4 + 0], v0);
        v1 = fmaf(a, pair_w[k * 4 + 1], v1);
        v2 = fmaf(a, pair_w[k * 4 + 2], v2);
        v3 = fmaf(a, pair_w[k * 4 + 3], v3);
    }
    size_t base = ((size_t)i * HH) * BAND + d;
    band[base + 0 * BAND] = v0;
    band[base + 1 * BAND] = v1;
    band[base + 2 * BAND] = v2;
    band[base + 3 * BAND] = v3;
}

// ---------------------------------------------------------------------------
// cond = t_emb + h_cond[token_idx] @ cond_proj_w + cond_proj_b   (M=4096,K=512,N=128)
// ---------------------------------------------------------------------------
__global__ __launch_bounds__(128) void k_cond(
    const float* __restrict__ h_cond, const int* __restrict__ tok,
    const float* __restrict__ W, const float* __restrict__ bias,
    const float* __restrict__ t_emb, float* __restrict__ cond)
{
    __shared__ float As[16][DMc];
    const int row0 = blockIdx.x * 16;
    const int tid = threadIdx.x;
    for (int idx = tid; idx < 16 * DMc; idx += 128) {
        int r = idx >> 9, k = idx & (DMc - 1);
        As[r][k] = h_cond[(size_t)tok[row0 + r] * DMc + k];
    }
    __syncthreads();
    const int c = tid;
    float acc[16];
    float base = t_emb[c] + bias[c];
    #pragma unroll
    for (int r = 0; r < 16; ++r) acc[r] = base;
    for (int k = 0; k < DMc; k += 2) {
        float w0 = W[k * DAq + c];
        float w1 = W[(k + 1) * DAq + c];
        #pragma unroll
        for (int r = 0; r < 16; ++r) {
            float2 a = *(const float2*)&As[r][k];
            acc[r] = fmaf(a.x, w0, acc[r]);
            acc[r] = fmaf(a.y, w1, acc[r]);
        }
    }
    #pragma unroll
    for (int r = 0; r < 16; ++r) cond[(size_t)(row0 + r) * DAq + c] = acc[r];
}

// ---------------------------------------------------------------------------
// [g,b] = cond @ aw + ab ;  out = (1+g) * LN(x; ln_g, ln_b) + b
// ln_g == nullptr -> plain LN (no affine). M=4096, K=128, N=256.
// ---------------------------------------------------------------------------
__global__ __launch_bounds__(256) void k_adaln_ln(
    const float* __restrict__ cond, const float* __restrict__ x,
    const float* __restrict__ aw, const float* __restrict__ ab,
    const float* __restrict__ ln_g, const float* __restrict__ ln_b,
    float* __restrict__ out)
{
    __shared__ float Cs[16][DAq];
    __shared__ float Xs[16][DAq];
    __shared__ float GB[16][256];
    __shared__ float mu[16], rs[16];
    const int row0 = blockIdx.x * 16;
    const int tid = threadIdx.x;
    for (int idx = tid; idx < 16 * DAq; idx += 256) {
        int r = idx >> 7, k = idx & 127;
        Cs[r][k] = cond[(size_t)(row0 + r) * DAq + k];
        Xs[r][k] = x[(size_t)(row0 + r) * DAq + k];
    }
    __syncthreads();

    const int c = tid;
    float acc[16];
    float b0 = ab[c];
    #pragma unroll
    for (int r = 0; r < 16; ++r) acc[r] = b0;
    for (int k = 0; k < DAq; k += 2) {
        float w0 = aw[k * 256 + c];
        float w1 = aw[(k + 1) * 256 + c];
        #pragma unroll
        for (int r = 0; r < 16; ++r) {
            float2 a = *(const float2*)&Cs[r][k];
            acc[r] = fmaf(a.x, w0, acc[r]);
            acc[r] = fmaf(a.y, w1, acc[r]);
        }
    }

    // LN stats: 16 lanes per row
    {
        int r = tid >> 4, s = tid & 15;
        float sum = 0.f, sq = 0.f;
        #pragma unroll
        for (int k = 0; k < DAq / 16; ++k) {
            float v = Xs[r][s + k * 16];
            sum += v; sq += v * v;
        }
        #pragma unroll
        for (int off = 8; off >= 1; off >>= 1) {
            sum += __shfl_xor(sum, off, 16);
            sq  += __shfl_xor(sq,  off, 16);
        }
        if (s == 0) {
            float m = sum * (1.0f / DAq);
            float v = sq * (1.0f / DAq) - m * m;
            mu[r] = m;
            rs[r] = rsqrtf(v + 1e-5f);
        }
    }
    #pragma unroll
    for (int r = 0; r < 16; ++r) GB[r][c] = acc[r];
    __syncthreads();

    for (int idx = tid; idx < 16 * DAq; idx += 256) {
        int r = idx >> 7, cc = idx & 127;
        float xn = (Xs[r][cc] - mu[r]) * rs[r];
        if (ln_g != nullptr) xn = xn * ln_g[cc] + ln_b[cc];
        float g1 = GB[r][cc], b1 = GB[r][128 + cc];
        out[(size_t)(row0 + r) * DAq + cc] = (1.0f + g1) * xn + b1;
    }
}

// ---------------------------------------------------------------------------
// Q,K,V,G = qn @ {wq,wk,wv,wg}   (M=4096, K=128, N=4x128)
// ---------------------------------------------------------------------------
__global__ __launch_bounds__(256) void k_qkvg(
    const float* __restrict__ qn,
    const float* __restrict__ wq, const float* __restrict__ wk,
    const float* __restrict__ wv, const float* __restrict__ wg,
    float* __restrict__ Qb, float* __restrict__ Kb,
    float* __restrict__ Vb, float* __restrict__ Gb)
{
    __shared__ float As[16][DAq];
    const int row0 = blockIdx.x * 16;
    const int tid = threadIdx.x;
    for (int idx = tid; idx < 16 * DAq; idx += 256) {
        int r = idx >> 7, k = idx & 127;
        As[r][k] = qn[(size_t)(row0 + r) * DAq + k];
    }
    __syncthreads();
    const int c = tid;
    const int cc = c & 127;
    const float* wlo = (c < 128) ? wq : wk;
    const float* whi = (c < 128) ? wv : wg;
    float* olo = (c < 128) ? Qb : Kb;
    float* ohi = (c < 128) ? Vb : Gb;
    float accL[16], accH[16];
    #pragma unroll
    for (int r = 0; r < 16; ++r) { accL[r] = 0.f; accH[r] = 0.f; }
    for (int k = 0; k < DAq; k += 2) {
        float wl0 = wlo[k * DAq + cc],       wh0 = whi[k * DAq + cc];
        float wl1 = wlo[(k + 1) * DAq + cc], wh1 = whi[(k + 1) * DAq + cc];
        #pragma unroll
        for (int r = 0; r < 16; ++r) {
            float2 a = *(const float2*)&As[r][k];
            accL[r] = fmaf(a.x, wl0, accL[r]);
            accL[r] = fmaf(a.y, wl1, accL[r]);
            accH[r] = fmaf(a.x, wh0, accH[r]);
            accH[r] = fmaf(a.y, wh1, accH[r]);
        }
    }
    #pragma unroll
    for (int r = 0; r < 16; ++r) {
        olo[(size_t)(row0 + r) * DAq + cc] = accL[r];
        ohi[(size_t)(row0 + r) * DAq + cc] = accH[r];
    }
}

// ---------------------------------------------------------------------------
// Banded attention: one thread per (i, h).
// ---------------------------------------------------------------------------
__global__ __launch_bounds__(256) void k_attn(
    const float* __restrict__ Qb, const float* __restrict__ Kb,
    const float* __restrict__ Vb, const float* __restrict__ band,
    float* __restrict__ att)
{
    int gid = blockIdx.x * 256 + threadIdx.x;   // 0..16383
    int i = gid >> 2, h = gid & 3;
    const float4* qv = (const float4*)(Qb + (size_t)i * DAq + h * DHh);
    float4 qr[8];
    #pragma unroll
    for (int t = 0; t < 8; ++t) qr[t] = qv[t];

    const float scale = 0.17677669529663687f;   // 1/sqrt(32)
    const float* brow = band + ((size_t)i * HH + h) * BAND;

    float s[BAND];
    float m = -1e30f;
    #pragma unroll
    for (int jo = 0; jo < BAND; ++jo) {
        int j = i - WIN + jo;
        float sv = -1e30f;
        if (j >= 0 && j < NA) {
            const float4* kv = (const float4*)(Kb + (size_t)j * DAq + h * DHh);
            float d = 0.f;
            #pragma unroll
            for (int t = 0; t < 8; ++t) {
                float4 kk = kv[t];
                d = fmaf(qr[t].x, kk.x, d);
                d = fmaf(qr[t].y, kk.y, d);
                d = fmaf(qr[t].z, kk.z, d);
                d = fmaf(qr[t].w, kk.w, d);
            }
            sv = fmaf(d, scale, brow[jo]);
        }
        s[jo] = sv;
        m = fmaxf(m, sv);
    }
    float l = 0.f;
    #pragma unroll
    for (int jo = 0; jo < BAND; ++jo) {
        float p = __expf(s[jo] - m);
        s[jo] = p;
        l += p;
    }
    float inv = 1.0f / l;

    float4 o[8];
    #pragma unroll
    for (int t = 0; t < 8; ++t) o[t] = make_float4(0.f, 0.f, 0.f, 0.f);
    #pragma unroll
    for (int jo = 0; jo < BAND; ++jo) {
        int j = i - WIN + jo;
        if (j >= 0 && j < NA) {
            const float4* vv = (const float4*)(Vb + (size_t)j * DAq + h * DHh);
            float p = s[jo];
            #pragma unroll
            for (int t = 0; t < 8; ++t) {
                float4 v = vv[t];
                o[t].x = fmaf(p, v.x, o[t].x);
                o[t].y = fmaf(p, v.y, o[t].y);
                o[t].z = fmaf(p, v.z, o[t].z);
                o[t].w = fmaf(p, v.w, o[t].w);
            }
        }
    }
    float4* ov = (float4*)(att + (size_t)i * DAq + h * DHh);
    #pragma unroll
    for (int t = 0; t < 8; ++t) {
        ov[t] = make_float4(o[t].x * inv, o[t].y * inv, o[t].z * inv, o[t].w * inv);
    }
}

// ---------------------------------------------------------------------------
// q1 = (q + sigmoid(G) * (att @ wo)) * (1 + sigmoid(c_atom @ g1w + g1b))
// ---------------------------------------------------------------------------
__global__ __launch_bounds__(128) void k_post(
    const float* __restrict__ att, const float* __restrict__ c_atom,
    const float* __restrict__ q, const float* __restrict__ Gb,
    const float* __restrict__ wo, const float* __restrict__ g1w,
    const float* __restrict__ g1b, float* __restrict__ q1)
{
    __shared__ float As[8][DAq];
    __shared__ float Bs[8][DAq];
    const int row0 = blockIdx.x * 8;
    const int tid = threadIdx.x;
    for (int idx = tid; idx < 8 * DAq; idx += 128) {
        int r = idx >> 7, k = idx & 127;
        As[r][k] = att[(size_t)(row0 + r) * DAq + k];
        Bs[r][k] = c_atom[(size_t)(row0 + r) * DAq + k];
    }
    __syncthreads();
    const int c = tid;
    float ao[8], ag[8];
    float gb = g1b[c];
    #pragma unroll
    for (int r = 0; r < 8; ++r) { ao[r] = 0.f; ag[r] = gb; }
    for (int k = 0; k < DAq; k += 2) {
        float wo0 = wo[k * DAq + c],        wg0 = g1w[k * DAq + c];
        float wo1 = wo[(k + 1) * DAq + c],  wg1 = g1w[(k + 1) * DAq + c];
        #pragma unroll
        for (int r = 0; r < 8; ++r) {
            float2 a = *(const float2*)&As[r][k];
            float2 bb = *(const float2*)&Bs[r][k];
            ao[r] = fmaf(a.x, wo0, ao[r]);
            ao[r] = fmaf(a.y, wo1, ao[r]);
            ag[r] = fmaf(bb.x, wg0, ag[r]);
            ag[r] = fmaf(bb.y, wg1, ag[r]);
        }
    }
    #pragma unroll
    for (int r = 0; r < 8; ++r) {
        size_t rowc = (size_t)(row0 + r) * DAq + c;
        float v = q[rowc] + sigmoidf_(Gb[rowc]) * ao[r];
        q1[rowc] = v * (1.0f + sigmoidf_(ag[r]));
    }
}

// ---------------------------------------------------------------------------
// hbuf = silu(qn2 @ sw1) * (qn2 @ sw3)   (M=4096, K=128, N=512)
// ---------------------------------------------------------------------------
__global__ __launch_bounds__(256) void k_swiglu(
    const float* __restrict__ qn2, const float* __restrict__ sw1,
    const float* __restrict__ sw3, float* __restrict__ hbuf)
{
    __shared__ float As[8][DAq];
    const int row0 = blockIdx.x * 8;
    const int tid = threadIdx.x;
    for (int idx = tid; idx < 8 * DAq; idx += 256) {
        int r = idx >> 7, k = idx & 127;
        As[r][k] = qn2[(size_t)(row0 + r) * DAq + k];
    }
    __syncthreads();
    const int c = tid, c2 = tid + 256;
    float a1a[8], a1b[8], a3a[8], a3b[8];
    #pragma unroll
    for (int r = 0; r < 8; ++r) { a1a[r] = a1b[r] = a3a[r] = a3b[r] = 0.f; }
    for (int k = 0; k < DAq; k += 2) {
        float w1a0 = sw1[k * DFf + c],  w1b0 = sw1[k * DFf + c2];
        float w3a0 = sw3[k * DFf + c],  w3b0 = sw3[k * DFf + c2];
        float w1a1 = sw1[(k + 1) * DFf + c],  w1b1 = sw1[(k + 1) * DFf + c2];
        float w3a1 = sw3[(k + 1) * DFf + c],  w3b1 = sw3[(k + 1) * DFf + c2];
        #pragma unroll
        for (int r = 0; r < 8; ++r) {
            float2 a = *(const float2*)&As[r][k];
            a1a[r] = fmaf(a.x, w1a0, a1a[r]); a1a[r] = fmaf(a.y, w1a1, a1a[r]);
            a1b[r] = fmaf(a.x, w1b0, a1b[r]); a1b[r] = fmaf(a.y, w1b1, a1b[r]);
            a3a[r] = fmaf(a.x, w3a0, a3a[r]); a3a[r] = fmaf(a.y, w3a1, a3a[r]);
            a3b[r] = fmaf(a.x, w3b0, a3b[r]); a3b[r] = fmaf(a.y, w3b1, a3b[r]);
        }
    }
    #pragma unroll
    for (int r = 0; r < 8; ++r) {
        size_t row = (size_t)(row0 + r) * DFf;
        float s1 = a1a[r];
        hbuf[row + c]  = (s1 * sigmoidf_(s1)) * a3a[r];
        float s1b = a1b[r];
        hbuf[row + c2] = (s1b * sigmoidf_(s1b)) * a3b[r];
    }
}

// ---------------------------------------------------------------------------
// out = q1 + sigmoid(c_atom @ g2w + g2b) * (hbuf @ sw2)
// ---------------------------------------------------------------------------
__global__ __launch_bounds__(128) void k_final(
    const float* __restrict__ hbuf, const float* __restrict__ c_atom,
    const float* __restrict__ q1, const float* __restrict__ sw2,
    const float* __restrict__ g2w, const float* __restrict__ g2b,
    float* __restrict__ out)
{
    __shared__ float Hs[8][DFf];
    __shared__ float Cs[8][DAq];
    const int row0 = blockIdx.x * 8;
    const int tid = threadIdx.x;
    for (int idx = tid; idx < 8 * DFf; idx += 128) {
        int r = idx >> 9, k = idx & (DFf - 1);
        Hs[r][k] = hbuf[(size_t)(row0 + r) * DFf + k];
    }
    for (int idx = tid; idx < 8 * DAq; idx += 128) {
        int r = idx >> 7, k = idx & 127;
        Cs[r][k] = c_atom[(size_t)(row0 + r) * DAq + k];
    }
    __syncthreads();
    const int c = tid;
    float as[8], ag[8];
    float gb = g2b[c];
    #pragma unroll
    for (int r = 0; r < 8; ++r) { as[r] = 0.f; ag[r] = gb; }
    for (int k = 0; k < DFf; k += 2) {
        float w0 = sw2[k * DAq + c];
        float w1 = sw2[(k + 1) * DAq + c];
        #pragma unroll
        for (int r = 0; r < 8; ++r) {
            float2 hh = *(const float2*)&Hs[r][k];
            as[r] = fmaf(hh.x, w0, as[r]);
            as[r] = fmaf(hh.y, w1, as[r]);
        }
    }
    for (int k = 0; k < DAq; k += 2) {
        float w0 = g2w[k * DAq + c];
        float w1 = g2w[(k + 1) * DAq + c];
        #pragma unroll
        for (int r = 0; r < 8; ++r) {
            float2 bb = *(const float2*)&Cs[r][k];
            ag[r] = fmaf(bb.x, w0, ag[r]);
            ag[r] = fmaf(bb.y, w1, ag[r]);
        }
    }
    #pragma unroll
    for (int r = 0; r < 8; ++r) {
        size_t rowc = (size_t)(row0 + r) * DAq + c;
        out[rowc] = q1[rowc] + sigmoidf_(ag[r]) * as[r];
    }
}

// ---------------------------------------------------------------------------
extern "C" void kernel_launch(void* const* d_in, const int* in_sizes, int n_in,
                              void* d_out, int out_size, void* d_ws, size_t ws_size,
                              hipStream_t stream)
{
    const float* q      = (const float*)d_in[0];
    const float* c_atom = (const float*)d_in[1];
    const float* h_cond = (const float*)d_in[2];
    const float* p_lm   = (const float*)d_in[3];
    const float* t_emb  = (const float*)d_in[4];
    const float* cond_w = (const float*)d_in[5];
    const float* cond_b = (const float*)d_in[6];
    const float* ad1w   = (const float*)d_in[7];
    const float* ad1b   = (const float*)d_in[8];
    const float* ad2w   = (const float*)d_in[9];
    const float* ad2b   = (const float*)d_in[10];
    const float* ln_g   = (const float*)d_in[11];
    const float* ln_b   = (const float*)d_in[12];
    const float* wq     = (const float*)d_in[13];
    const float* wk     = (const float*)d_in[14];
    const float* wv     = (const float*)d_in[15];
    const float* wg     = (const float*)d_in[16];
    const float* wo     = (const float*)d_in[17];
    const float* pair_w = (const float*)d_in[18];
    const float* pair_b = (const float*)d_in[19];
    const float* g1w    = (const float*)d_in[20];
    const float* g1b    = (const float*)d_in[21];
    const float* g2w    = (const float*)d_in[22];
    const float* g2b    = (const float*)d_in[23];
    const float* sw1    = (const float*)d_in[24];
    const float* sw3    = (const float*)d_in[25];
    const float* sw2    = (const float*)d_in[26];
    const int*   p_idx  = (const int*)d_in[27];
    const int*   tok    = (const int*)d_in[28];
    float* out = (float*)d_out;

    float* ws   = (float*)d_ws;
    float* cond = ws;
    float* qn   = ws + 524288;
    float* Qb   = ws + 1048576;
    float* Kb   = ws + 1572864;
    float* Vb   = ws + 2097152;
    float* Gb   = ws + 2621440;
    float* band = ws + 3145728;   // 4096*4*33 = 540672 floats
    float* att  = ws + 3686400;
    float* q1   = ws + 4210688;
    float* qn2  = ws + 4734976;
    float* hb   = ws + 5259264;   // 4096*512

    hipMemsetAsync(band, 0, (size_t)NA * HH * BAND * sizeof(float), stream);
    k_scatter<<<PPp / 256, 256, 0, stream>>>(p_lm, pair_w, pair_b, p_idx, band);
    k_cond<<<NA / 16, 128, 0, stream>>>(h_cond, tok, cond_w, cond_b, t_emb, cond);
    k_adaln_ln<<<NA / 16, 256, 0, stream>>>(cond, q, ad1w, ad1b, ln_g, ln_b, qn);
    k_qkvg<<<NA / 16, 256, 0, stream>>>(qn, wq, wk, wv, wg, Qb, Kb, Vb, Gb);
    k_attn<<<NA * HH / 256, 256, 0, stream>>>(Qb, Kb, Vb, band, att);
    k_post<<<NA / 8, 128, 0, stream>>>(att, c_atom, q, Gb, wo, g1w, g1b, q1);
    k_adaln_ln<<<NA / 16, 256, 0, stream>>>(cond, q1, ad2w, ad2b, nullptr, nullptr, qn2);
    k_swiglu<<<NA / 8, 256, 0, stream>>>(qn2, sw1, sw3, hb);
    k_final<<<NA / 8, 128, 0, stream>>>(hb, c_atom, q1, sw2, g2w, g2b, out);
}

// Round 2
// 342.123 us; speedup vs baseline: 1.0787x; 1.0787x over previous
//
#include <hip/hip_runtime.h>
#include <math.h>

#define NA   4096
#define DAq  128
#define DMc  512
#define HH   4
#define DFf  512
#define PPp  32768
#define WIN  16
#define BAND 33

__device__ __forceinline__ float sigmoidf_(float x) { return 1.0f / (1.0f + __expf(-x)); }

__device__ __forceinline__ void fma4(float4& acc, float a, const float4& w) {
    acc.x = fmaf(a, w.x, acc.x); acc.y = fmaf(a, w.y, acc.y);
    acc.z = fmaf(a, w.z, acc.z); acc.w = fmaf(a, w.w, acc.w);
}
__device__ __forceinline__ float4 sig4(float4 v) {
    return make_float4(sigmoidf_(v.x), sigmoidf_(v.y), sigmoidf_(v.z), sigmoidf_(v.w));
}

// ---------------------------------------------------------------------------
// Pair-bias scatter into banded buffer band[i][h][jo], jo = j-i+16
// ---------------------------------------------------------------------------
__global__ __launch_bounds__(256) void k_scatter(
    const float* __restrict__ p_lm, const float* __restrict__ pair_w,
    const float* __restrict__ pair_b, const int* __restrict__ idx,
    float* __restrict__ band)
{
    int p = blockIdx.x * 256 + threadIdx.x;
    if (p >= PPp) return;
    int i = idx[2 * p], j = idx[2 * p + 1];
    int d = j - i + WIN;
    if (d < 0 || d > 2 * WIN) return;
    float v0 = pair_b[0], v1 = pair_b[1], v2 = pair_b[2], v3 = pair_b[3];
    #pragma unroll
    for (int k = 0; k < 16; ++k) {
        float a = p_lm[p * 16 + k];
        v0 = fmaf(a, pair_w[k * 4 + 0], v0);
        v1 = fmaf(a, pair_w[k * 4 + 1], v1);
        v2 = fmaf(a, pair_w[k * 4 + 2], v2);
        v3 = fmaf(a, pair_w[k * 4 + 3], v3);
    }
    size_t base = ((size_t)i * HH) * BAND + d;
    band[base + 0 * BAND] = v0;
    band[base + 1 * BAND] = v1;
    band[base + 2 * BAND] = v2;
    band[base + 3 * BAND] = v3;
}

// ---------------------------------------------------------------------------
// cond = t_emb + h_cond[tok] @ W + b   (M=4096, K=512, N=128)
// grid (128, 2), 256 thr, BM=32, BN=64, thread = 2 rows x 4 cols
// ---------------------------------------------------------------------------
__global__ __launch_bounds__(256) void k_cond(
    const float* __restrict__ h_cond, const int* __restrict__ tok,
    const float* __restrict__ W, const float* __restrict__ bias,
    const float* __restrict__ t_emb, float* __restrict__ cond)
{
    __shared__ float As[32][128];
    const int row0 = blockIdx.x * 32;
    const int c0 = blockIdx.y * 64;
    const int tid = threadIdx.x;
    const int tx = tid & 15, ty = tid >> 4;
    const int col = c0 + tx * 4;
    float4 acc0 = {0,0,0,0}, acc1 = {0,0,0,0};
    for (int kc = 0; kc < DMc; kc += 128) {
        for (int i = tid; i < 1024; i += 256) {
            int r = i >> 5, cc = (i & 31) * 4;
            *(float4*)&As[r][cc] =
                *(const float4*)&h_cond[(size_t)tok[row0 + r] * DMc + kc + cc];
        }
        __syncthreads();
        #pragma unroll 8
        for (int k = 0; k < 128; k += 2) {
            float4 w0 = *(const float4*)&W[(size_t)(kc + k) * DAq + col];
            float4 w1 = *(const float4*)&W[(size_t)(kc + k + 1) * DAq + col];
            float2 a0 = *(const float2*)&As[ty * 2][k];
            float2 a1 = *(const float2*)&As[ty * 2 + 1][k];
            fma4(acc0, a0.x, w0); fma4(acc0, a0.y, w1);
            fma4(acc1, a1.x, w0); fma4(acc1, a1.y, w1);
        }
        __syncthreads();
    }
    float4 tb = *(const float4*)&t_emb[col];
    float4 bb = *(const float4*)&bias[col];
    acc0.x += tb.x + bb.x; acc0.y += tb.y + bb.y; acc0.z += tb.z + bb.z; acc0.w += tb.w + bb.w;
    acc1.x += tb.x + bb.x; acc1.y += tb.y + bb.y; acc1.z += tb.z + bb.z; acc1.w += tb.w + bb.w;
    *(float4*)&cond[(size_t)(row0 + ty * 2) * DAq + col] = acc0;
    *(float4*)&cond[(size_t)(row0 + ty * 2 + 1) * DAq + col] = acc1;
}

// ---------------------------------------------------------------------------
// [g,b] = cond @ aw + ab ;  out = (1+g) * LN(x) + b   (affine optional)
// grid (128, 2): block covers g-cols [c0,c0+64) and b-cols [c0+128,...)
// ---------------------------------------------------------------------------
__global__ __launch_bounds__(256) void k_adaln(
    const float* __restrict__ cond, const float* __restrict__ x,
    const float* __restrict__ aw, const float* __restrict__ ab,
    const float* __restrict__ ln_g, const float* __restrict__ ln_b,
    float* __restrict__ out, int affine)
{
    __shared__ float Cs[32][128];
    __shared__ float Xs[32][128];
    __shared__ float mu[32], rsd[32];
    const int row0 = blockIdx.x * 32;
    const int c0 = blockIdx.y * 64;
    const int tid = threadIdx.x;
    const int tx = tid & 15, ty = tid >> 4;
    const int col = c0 + tx * 4;
    for (int i = tid; i < 1024; i += 256) {
        int r = i >> 5, cc = (i & 31) * 4;
        *(float4*)&Cs[r][cc] = *(const float4*)&cond[(size_t)(row0 + r) * DAq + cc];
        *(float4*)&Xs[r][cc] = *(const float4*)&x[(size_t)(row0 + r) * DAq + cc];
    }
    __syncthreads();

    float4 ag0 = *(const float4*)&ab[col];
    float4 ab0 = *(const float4*)&ab[col + 128];
    float4 ag1 = ag0, ab1 = ab0;
    #pragma unroll 8
    for (int k = 0; k < 128; k += 2) {
        float4 wg0 = *(const float4*)&aw[(size_t)k * 256 + col];
        float4 wg1 = *(const float4*)&aw[(size_t)(k + 1) * 256 + col];
        float4 wb0 = *(const float4*)&aw[(size_t)k * 256 + col + 128];
        float4 wb1 = *(const float4*)&aw[(size_t)(k + 1) * 256 + col + 128];
        float2 a0 = *(const float2*)&Cs[ty * 2][k];
        float2 a1 = *(const float2*)&Cs[ty * 2 + 1][k];
        fma4(ag0, a0.x, wg0); fma4(ag0, a0.y, wg1);
        fma4(ab0, a0.x, wb0); fma4(ab0, a0.y, wb1);
        fma4(ag1, a1.x, wg0); fma4(ag1, a1.y, wg1);
        fma4(ab1, a1.x, wb0); fma4(ab1, a1.y, wb1);
    }

    // LN stats: 8 lanes per row
    {
        int r = tid >> 3, s = tid & 7;
        float sum = 0.f, sq = 0.f;
        #pragma unroll
        for (int kk = 0; kk < 16; ++kk) {
            float v = Xs[r][s + 8 * kk];
            sum += v; sq += v * v;
        }
        sum += __shfl_xor(sum, 1); sq += __shfl_xor(sq, 1);
        sum += __shfl_xor(sum, 2); sq += __shfl_xor(sq, 2);
        sum += __shfl_xor(sum, 4); sq += __shfl_xor(sq, 4);
        if (s == 0) {
            float m = sum * (1.0f / DAq);
            float v = sq * (1.0f / DAq) - m * m;
            mu[r] = m;
            rsd[r] = rsqrtf(v + 1e-5f);
        }
    }
    __syncthreads();

    float4 lg = make_float4(1,1,1,1), lb = make_float4(0,0,0,0);
    if (affine) {
        lg = *(const float4*)&ln_g[col];
        lb = *(const float4*)&ln_b[col];
    }
    #pragma unroll
    for (int rr = 0; rr < 2; ++rr) {
        int row = ty * 2 + rr;
        float4 xv = *(const float4*)&Xs[row][tx * 4 + c0];
        float m = mu[row], r = rsd[row];
        float4 g = rr ? ag1 : ag0;
        float4 b = rr ? ab1 : ab0;
        float4 o;
        o.x = (1.f + g.x) * (((xv.x - m) * r) * lg.x + lb.x) + b.x;
        o.y = (1.f + g.y) * (((xv.y - m) * r) * lg.y + lb.y) + b.y;
        o.z = (1.f + g.z) * (((xv.z - m) * r) * lg.z + lb.z) + b.z;
        o.w = (1.f + g.w) * (((xv.w - m) * r) * lg.w + lb.w) + b.w;
        *(float4*)&out[(size_t)(row0 + row) * DAq + col] = o;
    }
}

// ---------------------------------------------------------------------------
// Q,K,V,G = qn @ {wq,wk,wv,wg}   grid (128, 8): y>>1 = matrix, y&1 = col half
// ---------------------------------------------------------------------------
__global__ __launch_bounds__(256) void k_qkvg(
    const float* __restrict__ qn,
    const float* __restrict__ wq, const float* __restrict__ wk,
    const float* __restrict__ wv, const float* __restrict__ wg,
    float* __restrict__ Qb, float* __restrict__ Kb,
    float* __restrict__ Vb, float* __restrict__ Gb)
{
    __shared__ float As[32][128];
    const int row0 = blockIdx.x * 32;
    const int mat = blockIdx.y >> 1;
    const int c0 = (blockIdx.y & 1) * 64;
    const float* W = (mat == 0) ? wq : (mat == 1) ? wk : (mat == 2) ? wv : wg;
    float* O = (mat == 0) ? Qb : (mat == 1) ? Kb : (mat == 2) ? Vb : Gb;
    const int tid = threadIdx.x;
    const int tx = tid & 15, ty = tid >> 4;
    const int col = c0 + tx * 4;
    for (int i = tid; i < 1024; i += 256) {
        int r = i >> 5, cc = (i & 31) * 4;
        *(float4*)&As[r][cc] = *(const float4*)&qn[(size_t)(row0 + r) * DAq + cc];
    }
    __syncthreads();
    float4 acc0 = {0,0,0,0}, acc1 = {0,0,0,0};
    #pragma unroll 8
    for (int k = 0; k < 128; k += 2) {
        float4 w0 = *(const float4*)&W[(size_t)k * DAq + col];
        float4 w1 = *(const float4*)&W[(size_t)(k + 1) * DAq + col];
        float2 a0 = *(const float2*)&As[ty * 2][k];
        float2 a1 = *(const float2*)&As[ty * 2 + 1][k];
        fma4(acc0, a0.x, w0); fma4(acc0, a0.y, w1);
        fma4(acc1, a1.x, w0); fma4(acc1, a1.y, w1);
    }
    *(float4*)&O[(size_t)(row0 + ty * 2) * DAq + col] = acc0;
    *(float4*)&O[(size_t)(row0 + ty * 2 + 1) * DAq + col] = acc1;
}

// ---------------------------------------------------------------------------
// Banded attention: 4 lanes per (i,h), each owns an 8-dim quarter.
// ---------------------------------------------------------------------------
__global__ __launch_bounds__(256) void k_attn(
    const float* __restrict__ Qb, const float* __restrict__ Kb,
    const float* __restrict__ Vb, const float* __restrict__ band,
    float* __restrict__ att)
{
    int gid = blockIdx.x * 256 + threadIdx.x;   // 0..65535
    int qtr = gid & 3;
    int h = (gid >> 2) & 3;
    int i = gid >> 4;
    const float* qp = Qb + (size_t)i * DAq + h * 32 + qtr * 8;
    float4 q0 = *(const float4*)qp;
    float4 q1 = *(const float4*)(qp + 4);
    const float scale = 0.17677669529663687f;   // 1/sqrt(32)
    const float* brow = band + ((size_t)i * HH + h) * BAND;

    float s[BAND];
    float m = -1e30f;
    #pragma unroll
    for (int jo = 0; jo < BAND; ++jo) {
        int j = i - WIN + jo;
        float sv = -1e30f;
        if ((unsigned)j < NA) {       // uniform within the 4-lane shfl group
            const float* kp = Kb + (size_t)j * DAq + h * 32 + qtr * 8;
            float4 k0 = *(const float4*)kp;
            float4 k1 = *(const float4*)(kp + 4);
            float d = 0.f;
            d = fmaf(q0.x, k0.x, d); d = fmaf(q0.y, k0.y, d);
            d = fmaf(q0.z, k0.z, d); d = fmaf(q0.w, k0.w, d);
            d = fmaf(q1.x, k1.x, d); d = fmaf(q1.y, k1.y, d);
            d = fmaf(q1.z, k1.z, d); d = fmaf(q1.w, k1.w, d);
            d += __shfl_xor(d, 1);
            d += __shfl_xor(d, 2);
            sv = fmaf(d, scale, brow[jo]);
        }
        s[jo] = sv;
        m = fmaxf(m, sv);
    }
    float l = 0.f;
    #pragma unroll
    for (int jo = 0; jo < BAND; ++jo) {
        float p = __expf(s[jo] - m);
        s[jo] = p;
        l += p;
    }
    float inv = 1.0f / l;

    float4 o0 = {0,0,0,0}, o1 = {0,0,0,0};
    #pragma unroll
    for (int jo = 0; jo < BAND; ++jo) {
        int j = i - WIN + jo;
        if ((unsigned)j < NA) {
            const float* vp = Vb + (size_t)j * DAq + h * 32 + qtr * 8;
            float4 v0 = *(const float4*)vp;
            float4 v1 = *(const float4*)(vp + 4);
            float p = s[jo];
            fma4(o0, p, v0);
            fma4(o1, p, v1);
        }
    }
    float* op = att + (size_t)i * DAq + h * 32 + qtr * 8;
    *(float4*)op = make_float4(o0.x * inv, o0.y * inv, o0.z * inv, o0.w * inv);
    *(float4*)(op + 4) = make_float4(o1.x * inv, o1.y * inv, o1.z * inv, o1.w * inv);
}

// ---------------------------------------------------------------------------
// q1 = (q + sigmoid(G) * (att @ wo)) * (1 + sigmoid(c_atom @ g1w + g1b))
// ---------------------------------------------------------------------------
__global__ __launch_bounds__(256) void k_post(
    const float* __restrict__ att, const float* __restrict__ c_atom,
    const float* __restrict__ q, const float* __restrict__ Gb,
    const float* __restrict__ wo, const float* __restrict__ g1w,
    const float* __restrict__ g1b, float* __restrict__ q1)
{
    __shared__ float As[32][128];
    __shared__ float Bs[32][128];
    const int row0 = blockIdx.x * 32;
    const int c0 = blockIdx.y * 64;
    const int tid = threadIdx.x;
    const int tx = tid & 15, ty = tid >> 4;
    const int col = c0 + tx * 4;
    for (int i = tid; i < 1024; i += 256) {
        int r = i >> 5, cc = (i & 31) * 4;
        *(float4*)&As[r][cc] = *(const float4*)&att[(size_t)(row0 + r) * DAq + cc];
        *(float4*)&Bs[r][cc] = *(const float4*)&c_atom[(size_t)(row0 + r) * DAq + cc];
    }
    __syncthreads();
    float4 gb = *(const float4*)&g1b[col];
    float4 ao0 = {0,0,0,0}, ao1 = {0,0,0,0};
    float4 ag0 = gb, ag1 = gb;
    #pragma unroll 8
    for (int k = 0; k < 128; k += 2) {
        float4 wo0 = *(const float4*)&wo[(size_t)k * DAq + col];
        float4 wo1 = *(const float4*)&wo[(size_t)(k + 1) * DAq + col];
        float4 wg0 = *(const float4*)&g1w[(size_t)k * DAq + col];
        float4 wg1 = *(const float4*)&g1w[(size_t)(k + 1) * DAq + col];
        float2 a0 = *(const float2*)&As[ty * 2][k];
        float2 a1 = *(const float2*)&As[ty * 2 + 1][k];
        float2 b0 = *(const float2*)&Bs[ty * 2][k];
        float2 b1 = *(const float2*)&Bs[ty * 2 + 1][k];
        fma4(ao0, a0.x, wo0); fma4(ao0, a0.y, wo1);
        fma4(ao1, a1.x, wo0); fma4(ao1, a1.y, wo1);
        fma4(ag0, b0.x, wg0); fma4(ag0, b0.y, wg1);
        fma4(ag1, b1.x, wg0); fma4(ag1, b1.y, wg1);
    }
    #pragma unroll
    for (int rr = 0; rr < 2; ++rr) {
        int row = row0 + ty * 2 + rr;
        float4 qv = *(const float4*)&q[(size_t)row * DAq + col];
        float4 Gv = *(const float4*)&Gb[(size_t)row * DAq + col];
        float4 ao = rr ? ao1 : ao0;
        float4 ag = rr ? ag1 : ag0;
        float4 sG = sig4(Gv), sg = sig4(ag);
        float4 o;
        o.x = (qv.x + sG.x * ao.x) * (1.f + sg.x);
        o.y = (qv.y + sG.y * ao.y) * (1.f + sg.y);
        o.z = (qv.z + sG.z * ao.z) * (1.f + sg.z);
        o.w = (qv.w + sG.w * ao.w) * (1.f + sg.w);
        *(float4*)&q1[(size_t)row * DAq + col] = o;
    }
}

// ---------------------------------------------------------------------------
// hb = silu(qn2 @ sw1) * (qn2 @ sw3)   grid (128, 8)
// ---------------------------------------------------------------------------
__global__ __launch_bounds__(256) void k_swiglu(
    const float* __restrict__ qn2, const float* __restrict__ sw1,
    const float* __restrict__ sw3, float* __restrict__ hb)
{
    __shared__ float As[32][128];
    const int row0 = blockIdx.x * 32;
    const int c0 = blockIdx.y * 64;
    const int tid = threadIdx.x;
    const int tx = tid & 15, ty = tid >> 4;
    const int col = c0 + tx * 4;
    for (int i = tid; i < 1024; i += 256) {
        int r = i >> 5, cc = (i & 31) * 4;
        *(float4*)&As[r][cc] = *(const float4*)&qn2[(size_t)(row0 + r) * DAq + cc];
    }
    __syncthreads();
    float4 a10 = {0,0,0,0}, a11 = {0,0,0,0};
    float4 a30 = {0,0,0,0}, a31 = {0,0,0,0};
    #pragma unroll 8
    for (int k = 0; k < 128; k += 2) {
        float4 w10 = *(const float4*)&sw1[(size_t)k * DFf + col];
        float4 w11 = *(const float4*)&sw1[(size_t)(k + 1) * DFf + col];
        float4 w30 = *(const float4*)&sw3[(size_t)k * DFf + col];
        float4 w31 = *(const float4*)&sw3[(size_t)(k + 1) * DFf + col];
        float2 a0 = *(const float2*)&As[ty * 2][k];
        float2 a1 = *(const float2*)&As[ty * 2 + 1][k];
        fma4(a10, a0.x, w10); fma4(a10, a0.y, w11);
        fma4(a11, a1.x, w10); fma4(a11, a1.y, w11);
        fma4(a30, a0.x, w30); fma4(a30, a0.y, w31);
        fma4(a31, a1.x, w30); fma4(a31, a1.y, w31);
    }
    #pragma unroll
    for (int rr = 0; rr < 2; ++rr) {
        int row = row0 + ty * 2 + rr;
        float4 s1 = rr ? a11 : a10;
        float4 s3 = rr ? a31 : a30;
        float4 o;
        o.x = s1.x * sigmoidf_(s1.x) * s3.x;
        o.y = s1.y * sigmoidf_(s1.y) * s3.y;
        o.z = s1.z * sigmoidf_(s1.z) * s3.z;
        o.w = s1.w * sigmoidf_(s1.w) * s3.w;
        *(float4*)&hb[(size_t)row * DFf + col] = o;
    }
}

// ---------------------------------------------------------------------------
// out = q1 + sigmoid(c_atom @ g2w + g2b) * (hb @ sw2)
// ---------------------------------------------------------------------------
__global__ __launch_bounds__(256) void k_final(
    const float* __restrict__ hb, const float* __restrict__ c_atom,
    const float* __restrict__ q1, const float* __restrict__ sw2,
    const float* __restrict__ g2w, const float* __restrict__ g2b,
    float* __restrict__ out)
{
    __shared__ float Hs[32][128];
    __shared__ float Cs[32][128];
    const int row0 = blockIdx.x * 32;
    const int c0 = blockIdx.y * 64;
    const int tid = threadIdx.x;
    const int tx = tid & 15, ty = tid >> 4;
    const int col = c0 + tx * 4;
    for (int i = tid; i < 1024; i += 256) {
        int r = i >> 5, cc = (i & 31) * 4;
        *(float4*)&Cs[r][cc] = *(const float4*)&c_atom[(size_t)(row0 + r) * DAq + cc];
    }
    float4 as0 = {0,0,0,0}, as1 = {0,0,0,0};
    for (int kc = 0; kc < DFf; kc += 128) {
        __syncthreads();
        for (int i = tid; i < 1024; i += 256) {
            int r = i >> 5, cc = (i & 31) * 4;
            *(float4*)&Hs[r][cc] = *(const float4*)&hb[(size_t)(row0 + r) * DFf + kc + cc];
        }
        __syncthreads();
        #pragma unroll 8
        for (int k = 0; k < 128; k += 2) {
            float4 w0 = *(const float4*)&sw2[(size_t)(kc + k) * DAq + col];
            float4 w1 = *(const float4*)&sw2[(size_t)(kc + k + 1) * DAq + col];
            float2 h0 = *(const float2*)&Hs[ty * 2][k];
            float2 h1 = *(const float2*)&Hs[ty * 2 + 1][k];
            fma4(as0, h0.x, w0); fma4(as0, h0.y, w1);
            fma4(as1, h1.x, w0); fma4(as1, h1.y, w1);
        }
    }
    float4 gb = *(const float4*)&g2b[col];
    float4 ag0 = gb, ag1 = gb;
    #pragma unroll 8
    for (int k = 0; k < 128; k += 2) {
        float4 w0 = *(const float4*)&g2w[(size_t)k * DAq + col];
        float4 w1 = *(const float4*)&g2w[(size_t)(k + 1) * DAq + col];
        float2 b0 = *(const float2*)&Cs[ty * 2][k];
        float2 b1 = *(const float2*)&Cs[ty * 2 + 1][k];
        fma4(ag0, b0.x, w0); fma4(ag0, b0.y, w1);
        fma4(ag1, b1.x, w0); fma4(ag1, b1.y, w1);
    }
    #pragma unroll
    for (int rr = 0; rr < 2; ++rr) {
        int row = row0 + ty * 2 + rr;
        float4 qv = *(const float4*)&q1[(size_t)row * DAq + col];
        float4 as = rr ? as1 : as0;
        float4 ag = rr ? ag1 : ag0;
        float4 sg = sig4(ag);
        float4 o;
        o.x = qv.x + sg.x * as.x;
        o.y = qv.y + sg.y * as.y;
        o.z = qv.z + sg.z * as.z;
        o.w = qv.w + sg.w * as.w;
        *(float4*)&out[(size_t)row * DAq + col] = o;
    }
}

// ---------------------------------------------------------------------------
extern "C" void kernel_launch(void* const* d_in, const int* in_sizes, int n_in,
                              void* d_out, int out_size, void* d_ws, size_t ws_size,
                              hipStream_t stream)
{
    const float* q      = (const float*)d_in[0];
    const float* c_atom = (const float*)d_in[1];
    const float* h_cond = (const float*)d_in[2];
    const float* p_lm   = (const float*)d_in[3];
    const float* t_emb  = (const float*)d_in[4];
    const float* cond_w = (const float*)d_in[5];
    const float* cond_b = (const float*)d_in[6];
    const float* ad1w   = (const float*)d_in[7];
    const float* ad1b   = (const float*)d_in[8];
    const float* ad2w   = (const float*)d_in[9];
    const float* ad2b   = (const float*)d_in[10];
    const float* ln_g   = (const float*)d_in[11];
    const float* ln_b   = (const float*)d_in[12];
    const float* wq     = (const float*)d_in[13];
    const float* wk     = (const float*)d_in[14];
    const float* wv     = (const float*)d_in[15];
    const float* wg     = (const float*)d_in[16];
    const float* wo     = (const float*)d_in[17];
    const float* pair_w = (const float*)d_in[18];
    const float* pair_b = (const float*)d_in[19];
    const float* g1w    = (const float*)d_in[20];
    const float* g1b    = (const float*)d_in[21];
    const float* g2w    = (const float*)d_in[22];
    const float* g2b    = (const float*)d_in[23];
    const float* sw1    = (const float*)d_in[24];
    const float* sw3    = (const float*)d_in[25];
    const float* sw2    = (const float*)d_in[26];
    const int*   p_idx  = (const int*)d_in[27];
    const int*   tok    = (const int*)d_in[28];
    float* out = (float*)d_out;

    float* ws   = (float*)d_ws;
    float* cond = ws;
    float* qn   = ws + 524288;
    float* Qb   = ws + 1048576;
    float* Kb   = ws + 1572864;
    float* Vb   = ws + 2097152;
    float* Gb   = ws + 2621440;
    float* band = ws + 3145728;   // 4096*4*33 = 540672 floats
    float* att  = ws + 3686400;
    float* q1   = ws + 4210688;
    float* qn2  = ws + 4734976;
    float* hb   = ws + 5259264;   // 4096*512

    hipMemsetAsync(band, 0, (size_t)NA * HH * BAND * sizeof(float), stream);
    k_scatter<<<PPp / 256, 256, 0, stream>>>(p_lm, pair_w, pair_b, p_idx, band);
    k_cond<<<dim3(NA / 32, 2), 256, 0, stream>>>(h_cond, tok, cond_w, cond_b, t_emb, cond);
    k_adaln<<<dim3(NA / 32, 2), 256, 0, stream>>>(cond, q, ad1w, ad1b, ln_g, ln_b, qn, 1);
    k_qkvg<<<dim3(NA / 32, 8), 256, 0, stream>>>(qn, wq, wk, wv, wg, Qb, Kb, Vb, Gb);
    k_attn<<<NA * HH * 4 / 256, 256, 0, stream>>>(Qb, Kb, Vb, band, att);
    k_post<<<dim3(NA / 32, 2), 256, 0, stream>>>(att, c_atom, q, Gb, wo, g1w, g1b, q1);
    k_adaln<<<dim3(NA / 32, 2), 256, 0, stream>>>(cond, q1, ad2w, ad2b, ln_g, ln_b, qn2, 0);
    k_swiglu<<<dim3(NA / 32, 8), 256, 0, stream>>>(qn2, sw1, sw3, hb);
    k_final<<<dim3(NA / 32, 2), 256, 0, stream>>>(hb, c_atom, q1, sw2, g2w, g2b, out);
}

// Round 3
// 284.850 us; speedup vs baseline: 1.2956x; 1.2011x over previous
//
#include <hip/hip_runtime.h>
#include <math.h>

#define NA   4096
#define DAq  128
#define DMc  512
#define HH   4
#define DFf  512
#define PPp  32768
#define WIN  16
#define BAND 33

__device__ __forceinline__ float sigmoidf_(float x) { return 1.0f / (1.0f + __expf(-x)); }

__device__ __forceinline__ void fma4(float4& acc, float a, const float4& w) {
    acc.x = fmaf(a, w.x, acc.x); acc.y = fmaf(a, w.y, acc.y);
    acc.z = fmaf(a, w.z, acc.z); acc.w = fmaf(a, w.w, acc.w);
}
__device__ __forceinline__ float4 sig4(float4 v) {
    return make_float4(sigmoidf_(v.x), sigmoidf_(v.y), sigmoidf_(v.z), sigmoidf_(v.w));
}

// ---------------------------------------------------------------------------
// Pair-bias scatter into banded buffer band[i][h][jo], jo = j-i+16
// ---------------------------------------------------------------------------
__global__ __launch_bounds__(256) void k_scatter(
    const float* __restrict__ p_lm, const float* __restrict__ pair_w,
    const float* __restrict__ pair_b, const int* __restrict__ idx,
    float* __restrict__ band)
{
    int p = blockIdx.x * 256 + threadIdx.x;
    if (p >= PPp) return;
    int i = idx[2 * p], j = idx[2 * p + 1];
    int d = j - i + WIN;
    if (d < 0 || d > 2 * WIN) return;
    float v0 = pair_b[0], v1 = pair_b[1], v2 = pair_b[2], v3 = pair_b[3];
    #pragma unroll
    for (int k = 0; k < 16; ++k) {
        float a = p_lm[p * 16 + k];
        v0 = fmaf(a, pair_w[k * 4 + 0], v0);
        v1 = fmaf(a, pair_w[k * 4 + 1], v1);
        v2 = fmaf(a, pair_w[k * 4 + 2], v2);
        v3 = fmaf(a, pair_w[k * 4 + 3], v3);
    }
    size_t base = ((size_t)i * HH) * BAND + d;
    band[base + 0 * BAND] = v0;
    band[base + 1 * BAND] = v1;
    band[base + 2 * BAND] = v2;
    band[base + 3 * BAND] = v3;
}

// ---------------------------------------------------------------------------
// cond partial GEMM: cond_part[z] = h_cond[tok] @ W[z*256:(z+1)*256, :]
// grid (128, 2, 2): x = M-tile(32), y = N-half(64), z = K-half(256)
// ---------------------------------------------------------------------------
__global__ __launch_bounds__(256) void k_cond(
    const float* __restrict__ h_cond, const int* __restrict__ tok,
    const float* __restrict__ W, float* __restrict__ cond_part)
{
    __shared__ float As[32][260];
    const int row0 = blockIdx.x * 32;
    const int c0 = blockIdx.y * 64;
    const int kc0 = blockIdx.z * 256;
    const int tid = threadIdx.x;
    for (int i = tid; i < 2048; i += 256) {
        int r = i >> 6, cc = (i & 63) * 4;
        *(float4*)&As[r][cc] =
            *(const float4*)&h_cond[(size_t)tok[row0 + r] * DMc + kc0 + cc];
    }
    __syncthreads();
    const int tx = tid & 15, ty = tid >> 4;
    const int col = c0 + tx * 4;
    float4 acc0 = {0,0,0,0}, acc1 = {0,0,0,0};
    #pragma unroll 8
    for (int k = 0; k < 256; k += 2) {
        float4 w0 = *(const float4*)&W[(size_t)(kc0 + k) * DAq + col];
        float4 w1 = *(const float4*)&W[(size_t)(kc0 + k + 1) * DAq + col];
        float2 a0 = *(const float2*)&As[ty * 2][k];
        float2 a1 = *(const float2*)&As[ty * 2 + 1][k];
        fma4(acc0, a0.x, w0); fma4(acc0, a0.y, w1);
        fma4(acc1, a1.x, w0); fma4(acc1, a1.y, w1);
    }
    float* outp = cond_part + (size_t)blockIdx.z * NA * DAq;
    *(float4*)&outp[(size_t)(row0 + ty * 2) * DAq + col] = acc0;
    *(float4*)&outp[(size_t)(row0 + ty * 2 + 1) * DAq + col] = acc1;
}

// ---------------------------------------------------------------------------
// gb1/gb2 (from cond = p0+p1+t_emb+cond_b) and sigmoid gates (from c_atom).
// grid (128, 12): y<4 gb1 | y<8 gb2 | y<10 gate1 | y<12 gate2
// ---------------------------------------------------------------------------
__global__ __launch_bounds__(256) void k_mods(
    const float* __restrict__ cond_part, const float* __restrict__ t_emb,
    const float* __restrict__ cond_b, const float* __restrict__ c_atom,
    const float* __restrict__ ad1w, const float* __restrict__ ad1b,
    const float* __restrict__ ad2w, const float* __restrict__ ad2b,
    const float* __restrict__ g1w, const float* __restrict__ g1b,
    const float* __restrict__ g2w, const float* __restrict__ g2b,
    float* __restrict__ gb1, float* __restrict__ gb2,
    float* __restrict__ gate1, float* __restrict__ gate2)
{
    __shared__ float As[32][132];
    const int row0 = blockIdx.x * 32;
    const int y = blockIdx.y;
    const int tid = threadIdx.x;
    const bool condA = (y < 8);
    for (int i = tid; i < 1024; i += 256) {
        int r = i >> 5, cc = (i & 31) * 4;
        float4 v;
        if (condA) {
            float4 p0 = *(const float4*)&cond_part[(size_t)(row0 + r) * DAq + cc];
            float4 p1 = *(const float4*)&cond_part[(size_t)NA * DAq + (size_t)(row0 + r) * DAq + cc];
            float4 te = *(const float4*)&t_emb[cc];
            float4 cb = *(const float4*)&cond_b[cc];
            v = make_float4(p0.x + p1.x + te.x + cb.x, p0.y + p1.y + te.y + cb.y,
                            p0.z + p1.z + te.z + cb.z, p0.w + p1.w + te.w + cb.w);
        } else {
            v = *(const float4*)&c_atom[(size_t)(row0 + r) * DAq + cc];
        }
        *(float4*)&As[r][cc] = v;
    }
    __syncthreads();

    const float* W; const float* bias; float* O; int ldw; int colg; bool sig;
    if (y < 4)       { W = ad1w; bias = ad1b; O = gb1;   ldw = 256; colg = y * 64;        sig = false; }
    else if (y < 8)  { W = ad2w; bias = ad2b; O = gb2;   ldw = 256; colg = (y - 4) * 64;  sig = false; }
    else if (y < 10) { W = g1w;  bias = g1b;  O = gate1; ldw = 128; colg = (y - 8) * 64;  sig = true; }
    else             { W = g2w;  bias = g2b;  O = gate2; ldw = 128; colg = (y - 10) * 64; sig = true; }

    const int tx = tid & 15, ty = tid >> 4;
    const int col = colg + tx * 4;
    float4 b0 = *(const float4*)&bias[col];
    float4 acc0 = b0, acc1 = b0;
    #pragma unroll 8
    for (int k = 0; k < 128; k += 2) {
        float4 w0 = *(const float4*)&W[(size_t)k * ldw + col];
        float4 w1 = *(const float4*)&W[(size_t)(k + 1) * ldw + col];
        float2 a0 = *(const float2*)&As[ty * 2][k];
        float2 a1 = *(const float2*)&As[ty * 2 + 1][k];
        fma4(acc0, a0.x, w0); fma4(acc0, a0.y, w1);
        fma4(acc1, a1.x, w0); fma4(acc1, a1.y, w1);
    }
    if (sig) { acc0 = sig4(acc0); acc1 = sig4(acc1); }
    *(float4*)&O[(size_t)(row0 + ty * 2) * ldw + col] = acc0;
    *(float4*)&O[(size_t)(row0 + ty * 2 + 1) * ldw + col] = acc1;
}

// ---------------------------------------------------------------------------
// qn = (1+g1)*LN(q;ln_g,ln_b)+b1 (in LDS), then qn @ {wq,wk,wv,wg}
// grid (128, 8): y>>1 = matrix, y&1 = col half
// ---------------------------------------------------------------------------
__global__ __launch_bounds__(256) void k_qkvg(
    const float* __restrict__ q, const float* __restrict__ gb1,
    const float* __restrict__ ln_g, const float* __restrict__ ln_b,
    const float* __restrict__ wq, const float* __restrict__ wk,
    const float* __restrict__ wv, const float* __restrict__ wg,
    float* __restrict__ Qb, float* __restrict__ Kb,
    float* __restrict__ Vb, float* __restrict__ Gb)
{
    __shared__ float Xs[32][132];
    __shared__ float mu[32], rsd[32];
    const int row0 = blockIdx.x * 32;
    const int mat = blockIdx.y >> 1;
    const int c0 = (blockIdx.y & 1) * 64;
    const float* W = (mat == 0) ? wq : (mat == 1) ? wk : (mat == 2) ? wv : wg;
    float* O = (mat == 0) ? Qb : (mat == 1) ? Kb : (mat == 2) ? Vb : Gb;
    const int tid = threadIdx.x;

    for (int i = tid; i < 1024; i += 256) {
        int r = i >> 5, cc = (i & 31) * 4;
        *(float4*)&Xs[r][cc] = *(const float4*)&q[(size_t)(row0 + r) * DAq + cc];
    }
    __syncthreads();
    {
        int r = tid >> 3, s = tid & 7;
        float sum = 0.f, sq = 0.f;
        #pragma unroll
        for (int kk = 0; kk < 4; ++kk) {
            float4 v = *(const float4*)&Xs[r][s * 4 + kk * 32];
            sum += v.x + v.y + v.z + v.w;
            sq += v.x * v.x + v.y * v.y + v.z * v.z + v.w * v.w;
        }
        sum += __shfl_xor(sum, 1); sq += __shfl_xor(sq, 1);
        sum += __shfl_xor(sum, 2); sq += __shfl_xor(sq, 2);
        sum += __shfl_xor(sum, 4); sq += __shfl_xor(sq, 4);
        if (s == 0) {
            float m = sum * (1.0f / DAq);
            float v = sq * (1.0f / DAq) - m * m;
            mu[r] = m;
            rsd[r] = rsqrtf(v + 1e-5f);
        }
    }
    __syncthreads();
    for (int i = tid; i < 1024; i += 256) {
        int r = i >> 5, cc = (i & 31) * 4;
        int row = row0 + r;
        float4 xv = *(float4*)&Xs[r][cc];
        float4 g = *(const float4*)&gb1[(size_t)row * 256 + cc];
        float4 b = *(const float4*)&gb1[(size_t)row * 256 + 128 + cc];
        float4 lg = *(const float4*)&ln_g[cc];
        float4 lb = *(const float4*)&ln_b[cc];
        float m = mu[r], rs = rsd[r];
        float4 o;
        o.x = (1.f + g.x) * (((xv.x - m) * rs) * lg.x + lb.x) + b.x;
        o.y = (1.f + g.y) * (((xv.y - m) * rs) * lg.y + lb.y) + b.y;
        o.z = (1.f + g.z) * (((xv.z - m) * rs) * lg.z + lb.z) + b.z;
        o.w = (1.f + g.w) * (((xv.w - m) * rs) * lg.w + lb.w) + b.w;
        *(float4*)&Xs[r][cc] = o;
    }
    __syncthreads();

    const int tx = tid & 15, ty = tid >> 4;
    const int col = c0 + tx * 4;
    float4 acc0 = {0,0,0,0}, acc1 = {0,0,0,0};
    #pragma unroll 8
    for (int k = 0; k < 128; k += 2) {
        float4 w0 = *(const float4*)&W[(size_t)k * DAq + col];
        float4 w1 = *(const float4*)&W[(size_t)(k + 1) * DAq + col];
        float2 a0 = *(const float2*)&Xs[ty * 2][k];
        float2 a1 = *(const float2*)&Xs[ty * 2 + 1][k];
        fma4(acc0, a0.x, w0); fma4(acc0, a0.y, w1);
        fma4(acc1, a1.x, w0); fma4(acc1, a1.y, w1);
    }
    *(float4*)&O[(size_t)(row0 + ty * 2) * DAq + col] = acc0;
    *(float4*)&O[(size_t)(row0 + ty * 2 + 1) * DAq + col] = acc1;
}

// ---------------------------------------------------------------------------
// Fused banded attention + wo + gating: block = 8 atom rows.
// Phase 1: 8 lanes per (i,h), lane owns 4 dims of 32 -> att tile in LDS.
// Phase 2: q1 = (q + sig(G)*(att@wo)) * (1+gate1)
// ---------------------------------------------------------------------------
__global__ __launch_bounds__(256) void k_attn(
    const float* __restrict__ Qb, const float* __restrict__ Kb,
    const float* __restrict__ Vb, const float* __restrict__ Gb,
    const float* __restrict__ band, const float* __restrict__ q,
    const float* __restrict__ gate1, const float* __restrict__ wo,
    float* __restrict__ q1)
{
    __shared__ float att_s[8][132];
    const int row0 = blockIdx.x * 8;
    const int tid = threadIdx.x;
    {
        const int g = tid >> 3, l = tid & 7;
        const int i = row0 + (g >> 2), h = g & 3;
        const float scale = 0.17677669529663687f;   // 1/sqrt(32)
        float4 qr = *(const float4*)(Qb + (size_t)i * DAq + h * 32 + l * 4);
        const float* brow = band + ((size_t)i * HH + h) * BAND;

        float s[BAND];
        float m = -1e30f;
        #pragma unroll
        for (int jo = 0; jo < BAND; ++jo) {
            int j = i - WIN + jo;
            float sv = -1e30f;
            if ((unsigned)j < NA) {
                float4 kk = *(const float4*)(Kb + (size_t)j * DAq + h * 32 + l * 4);
                float d = 0.f;
                d = fmaf(qr.x, kk.x, d); d = fmaf(qr.y, kk.y, d);
                d = fmaf(qr.z, kk.z, d); d = fmaf(qr.w, kk.w, d);
                d += __shfl_xor(d, 1);
                d += __shfl_xor(d, 2);
                d += __shfl_xor(d, 4);
                sv = fmaf(d, scale, brow[jo]);
            }
            s[jo] = sv;
            m = fmaxf(m, sv);
        }
        float lsum = 0.f;
        #pragma unroll
        for (int jo = 0; jo < BAND; ++jo) {
            float p = __expf(s[jo] - m);
            s[jo] = p;
            lsum += p;
        }
        float inv = 1.0f / lsum;
        float4 o = {0,0,0,0};
        #pragma unroll
        for (int jo = 0; jo < BAND; ++jo) {
            int j = i - WIN + jo;
            if ((unsigned)j < NA) {
                float4 v = *(const float4*)(Vb + (size_t)j * DAq + h * 32 + l * 4);
                fma4(o, s[jo], v);
            }
        }
        *(float4*)&att_s[g >> 2][h * 32 + l * 4] =
            make_float4(o.x * inv, o.y * inv, o.z * inv, o.w * inv);
    }
    __syncthreads();

    const int r = tid >> 5;
    const int col = (tid & 31) * 4;
    const int row = row0 + r;
    float4 acc = {0,0,0,0};
    #pragma unroll 8
    for (int k = 0; k < 128; ++k) {
        float4 w = *(const float4*)&wo[(size_t)k * DAq + col];
        float a = att_s[r][k];
        fma4(acc, a, w);
    }
    float4 qv = *(const float4*)&q[(size_t)row * DAq + col];
    float4 Gv = *(const float4*)&Gb[(size_t)row * DAq + col];
    float4 g1v = *(const float4*)&gate1[(size_t)row * DAq + col];
    float4 sG = sig4(Gv);
    float4 o;
    o.x = (qv.x + sG.x * acc.x) * (1.f + g1v.x);
    o.y = (qv.y + sG.y * acc.y) * (1.f + g1v.y);
    o.z = (qv.z + sG.z * acc.z) * (1.f + g1v.z);
    o.w = (qv.w + sG.w * acc.w) * (1.f + g1v.w);
    *(float4*)&q1[(size_t)row * DAq + col] = o;
}

// ---------------------------------------------------------------------------
// Fused FFN: qn2 = (1+g2)*LN(q1)+b2; hb = silu(qn2@sw1)*(qn2@sw3) in LDS;
// out = q1 + gate2 * (hb @ sw2).  Block = 8 rows, grid 512.
// ---------------------------------------------------------------------------
__global__ __launch_bounds__(256) void k_ffn(
    const float* __restrict__ q1g, const float* __restrict__ gb2,
    const float* __restrict__ gate2, const float* __restrict__ sw1,
    const float* __restrict__ sw3, const float* __restrict__ sw2,
    float* __restrict__ out)
{
    __shared__ float q1s[8][132];
    __shared__ float qn2s[8][132];
    __shared__ float hbs[8][516];
    __shared__ float mu[8], rsd[8];
    const int row0 = blockIdx.x * 8;
    const int tid = threadIdx.x;
    {
        int r = tid >> 5, cc = (tid & 31) * 4;
        *(float4*)&q1s[r][cc] = *(const float4*)&q1g[(size_t)(row0 + r) * DAq + cc];
    }
    __syncthreads();
    {
        int r = tid >> 5, s = tid & 31;
        float4 v = *(const float4*)&q1s[r][s * 4];
        float sum = v.x + v.y + v.z + v.w;
        float sq = v.x * v.x + v.y * v.y + v.z * v.z + v.w * v.w;
        sum += __shfl_xor(sum, 1);  sq += __shfl_xor(sq, 1);
        sum += __shfl_xor(sum, 2);  sq += __shfl_xor(sq, 2);
        sum += __shfl_xor(sum, 4);  sq += __shfl_xor(sq, 4);
        sum += __shfl_xor(sum, 8);  sq += __shfl_xor(sq, 8);
        sum += __shfl_xor(sum, 16); sq += __shfl_xor(sq, 16);
        if (s == 0) {
            float m = sum * (1.0f / DAq);
            float vv = sq * (1.0f / DAq) - m * m;
            mu[r] = m;
            rsd[r] = rsqrtf(vv + 1e-5f);
        }
    }
    __syncthreads();
    {
        int r = tid >> 5, cc = (tid & 31) * 4;
        int row = row0 + r;
        float4 xv = *(float4*)&q1s[r][cc];
        float4 g = *(const float4*)&gb2[(size_t)row * 256 + cc];
        float4 b = *(const float4*)&gb2[(size_t)row * 256 + 128 + cc];
        float m = mu[r], rs = rsd[r];
        float4 o;
        o.x = (1.f + g.x) * ((xv.x - m) * rs) + b.x;
        o.y = (1.f + g.y) * ((xv.y - m) * rs) + b.y;
        o.z = (1.f + g.z) * ((xv.z - m) * rs) + b.z;
        o.w = (1.f + g.w) * ((xv.w - m) * rs) + b.w;
        *(float4*)&qn2s[r][cc] = o;
    }
    __syncthreads();
    {
        const int ty = tid >> 6, tx = tid & 63;
        const int c = tx * 8;
        float4 a1_00 = {0,0,0,0}, a1_01 = {0,0,0,0}, a1_10 = {0,0,0,0}, a1_11 = {0,0,0,0};
        float4 a3_00 = {0,0,0,0}, a3_01 = {0,0,0,0}, a3_10 = {0,0,0,0}, a3_11 = {0,0,0,0};
        #pragma unroll 4
        for (int k = 0; k < 128; ++k) {
            float4 w1a = *(const float4*)&sw1[(size_t)k * DFf + c];
            float4 w1b = *(const float4*)&sw1[(size_t)k * DFf + c + 4];
            float4 w3a = *(const float4*)&sw3[(size_t)k * DFf + c];
            float4 w3b = *(const float4*)&sw3[(size_t)k * DFf + c + 4];
            float a0 = qn2s[2 * ty][k];
            float a1 = qn2s[2 * ty + 1][k];
            fma4(a1_00, a0, w1a); fma4(a1_01, a0, w1b);
            fma4(a1_10, a1, w1a); fma4(a1_11, a1, w1b);
            fma4(a3_00, a0, w3a); fma4(a3_01, a0, w3b);
            fma4(a3_10, a1, w3a); fma4(a3_11, a1, w3b);
        }
        float4 h;
        h.x = a1_00.x * sigmoidf_(a1_00.x) * a3_00.x;
        h.y = a1_00.y * sigmoidf_(a1_00.y) * a3_00.y;
        h.z = a1_00.z * sigmoidf_(a1_00.z) * a3_00.z;
        h.w = a1_00.w * sigmoidf_(a1_00.w) * a3_00.w;
        *(float4*)&hbs[2 * ty][c] = h;
        h.x = a1_01.x * sigmoidf_(a1_01.x) * a3_01.x;
        h.y = a1_01.y * sigmoidf_(a1_01.y) * a3_01.y;
        h.z = a1_01.z * sigmoidf_(a1_01.z) * a3_01.z;
        h.w = a1_01.w * sigmoidf_(a1_01.w) * a3_01.w;
        *(float4*)&hbs[2 * ty][c + 4] = h;
        h.x = a1_10.x * sigmoidf_(a1_10.x) * a3_10.x;
        h.y = a1_10.y * sigmoidf_(a1_10.y) * a3_10.y;
        h.z = a1_10.z * sigmoidf_(a1_10.z) * a3_10.z;
        h.w = a1_10.w * sigmoidf_(a1_10.w) * a3_10.w;
        *(float4*)&hbs[2 * ty + 1][c] = h;
        h.x = a1_11.x * sigmoidf_(a1_11.x) * a3_11.x;
        h.y = a1_11.y * sigmoidf_(a1_11.y) * a3_11.y;
        h.z = a1_11.z * sigmoidf_(a1_11.z) * a3_11.z;
        h.w = a1_11.w * sigmoidf_(a1_11.w) * a3_11.w;
        *(float4*)&hbs[2 * ty + 1][c + 4] = h;
    }
    __syncthreads();
    {
        const int r = tid >> 5;
        const int col = (tid & 31) * 4;
        const int row = row0 + r;
        float4 acc = {0,0,0,0};
        #pragma unroll 16
        for (int k = 0; k < 512; ++k) {
            float4 w = *(const float4*)&sw2[(size_t)k * DAq + col];
            float a = hbs[r][k];
            fma4(acc, a, w);
        }
        float4 qv = *(float4*)&q1s[r][col];
        float4 g2 = *(const float4*)&gate2[(size_t)row * DAq + col];
        float4 o;
        o.x = qv.x + g2.x * acc.x;
        o.y = qv.y + g2.y * acc.y;
        o.z = qv.z + g2.z * acc.z;
        o.w = qv.w + g2.w * acc.w;
        *(float4*)&out[(size_t)row * DAq + col] = o;
    }
}

// ---------------------------------------------------------------------------
extern "C" void kernel_launch(void* const* d_in, const int* in_sizes, int n_in,
                              void* d_out, int out_size, void* d_ws, size_t ws_size,
                              hipStream_t stream)
{
    const float* q      = (const float*)d_in[0];
    const float* c_atom = (const float*)d_in[1];
    const float* h_cond = (const float*)d_in[2];
    const float* p_lm   = (const float*)d_in[3];
    const float* t_emb  = (const float*)d_in[4];
    const float* cond_w = (const float*)d_in[5];
    const float* cond_b = (const float*)d_in[6];
    const float* ad1w   = (const float*)d_in[7];
    const float* ad1b   = (const float*)d_in[8];
    const float* ad2w   = (const float*)d_in[9];
    const float* ad2b   = (const float*)d_in[10];
    const float* ln_g   = (const float*)d_in[11];
    const float* ln_b   = (const float*)d_in[12];
    const float* wq     = (const float*)d_in[13];
    const float* wk     = (const float*)d_in[14];
    const float* wv     = (const float*)d_in[15];
    const float* wg     = (const float*)d_in[16];
    const float* wo     = (const float*)d_in[17];
    const float* pair_w = (const float*)d_in[18];
    const float* pair_b = (const float*)d_in[19];
    const float* g1w    = (const float*)d_in[20];
    const float* g1b    = (const float*)d_in[21];
    const float* g2w    = (const float*)d_in[22];
    const float* g2b    = (const float*)d_in[23];
    const float* sw1    = (const float*)d_in[24];
    const float* sw3    = (const float*)d_in[25];
    const float* sw2    = (const float*)d_in[26];
    const int*   p_idx  = (const int*)d_in[27];
    const int*   tok    = (const int*)d_in[28];
    float* out = (float*)d_out;

    float* ws     = (float*)d_ws;
    float* cond_p = ws;                  // 2 x 4096x128
    float* gb1    = ws + 1048576;        // 4096x256
    float* gb2    = ws + 2097152;        // 4096x256
    float* gate1  = ws + 3145728;        // 4096x128 (sigmoid applied)
    float* gate2  = ws + 3670016;        // 4096x128 (sigmoid applied)
    float* Qb     = ws + 4194304;
    float* Kb     = ws + 4718592;
    float* Vb     = ws + 5242880;
    float* Gb     = ws + 5767168;
    float* band   = ws + 6291456;        // 4096x4x33
    float* q1     = ws + 6832128;        // 4096x128

    hipMemsetAsync(band, 0, (size_t)NA * HH * BAND * sizeof(float), stream);
    k_scatter<<<PPp / 256, 256, 0, stream>>>(p_lm, pair_w, pair_b, p_idx, band);
    k_cond<<<dim3(NA / 32, 2, 2), 256, 0, stream>>>(h_cond, tok, cond_w, cond_p);
    k_mods<<<dim3(NA / 32, 12), 256, 0, stream>>>(cond_p, t_emb, cond_b, c_atom,
                                                  ad1w, ad1b, ad2w, ad2b,
                                                  g1w, g1b, g2w, g2b,
                                                  gb1, gb2, gate1, gate2);
    k_qkvg<<<dim3(NA / 32, 8), 256, 0, stream>>>(q, gb1, ln_g, ln_b,
                                                 wq, wk, wv, wg, Qb, Kb, Vb, Gb);
    k_attn<<<NA / 8, 256, 0, stream>>>(Qb, Kb, Vb, Gb, band, q, gate1, wo, q1);
    k_ffn<<<NA / 8, 256, 0, stream>>>(q1, gb2, gate2, sw1, sw3, sw2, out);
}

// Round 4
// 206.507 us; speedup vs baseline: 1.7871x; 1.3794x over previous
//
#include <hip/hip_runtime.h>
#include <math.h>

#define NA   4096
#define DA   128
#define DM   512
#define NT   1024
#define HH   4
#define DF   512
#define PP   32768
#define WIN  16
#define BAND 33

typedef __attribute__((ext_vector_type(8))) short bf16x8;
typedef __attribute__((ext_vector_type(4))) float f32x4;

__device__ __forceinline__ float sigmoidf_(float x) { return 1.0f / (1.0f + __expf(-x)); }
__device__ __forceinline__ ushort f2bf(float f) {
    union { float f; unsigned int i; } x; x.f = f;
    unsigned int r = x.i + 0x7fffu + ((x.i >> 16) & 1u);
    return (ushort)(r >> 16);
}

// ---------------------------------------------------------------------------
// Prep: convert weights to bf16, transposed to WT[N][K]; h_cond/c_atom to bf16.
// ---------------------------------------------------------------------------
__global__ __launch_bounds__(256) void k_prep(
    const float* __restrict__ hc, const float* __restrict__ ca,
    const float* __restrict__ cw, const float* __restrict__ a1, const float* __restrict__ a2,
    const float* __restrict__ wq, const float* __restrict__ wk, const float* __restrict__ wv,
    const float* __restrict__ wg, const float* __restrict__ wo,
    const float* __restrict__ g1, const float* __restrict__ g2,
    const float* __restrict__ s1, const float* __restrict__ s3, const float* __restrict__ s2,
    ushort* hcb, ushort* cab, ushort* cwT, ushort* a1T, ushort* a2T,
    ushort* wqT, ushort* wkT, ushort* wvT, ushort* wgT, ushort* woT,
    ushort* g1T, ushort* g2T, ushort* s1T, ushort* s3T, ushort* s2T)
{
    const float* src; ushort* dst; int logK = 0, N = 0, total = 0, tr = 1;
    switch (blockIdx.y) {
        case 0:  src = hc; dst = hcb; total = NT * DM; tr = 0; break;
        case 1:  src = ca; dst = cab; total = NA * DA; tr = 0; break;
        case 2:  src = cw; dst = cwT; logK = 9; N = 128; break;
        case 3:  src = a1; dst = a1T; logK = 7; N = 256; break;
        case 4:  src = a2; dst = a2T; logK = 7; N = 256; break;
        case 5:  src = wq; dst = wqT; logK = 7; N = 128; break;
        case 6:  src = wk; dst = wkT; logK = 7; N = 128; break;
        case 7:  src = wv; dst = wvT; logK = 7; N = 128; break;
        case 8:  src = wg; dst = wgT; logK = 7; N = 128; break;
        case 9:  src = wo; dst = woT; logK = 7; N = 128; break;
        case 10: src = g1; dst = g1T; logK = 7; N = 128; break;
        case 11: src = g2; dst = g2T; logK = 7; N = 128; break;
        case 12: src = s1; dst = s1T; logK = 7; N = 512; break;
        case 13: src = s3; dst = s3T; logK = 7; N = 512; break;
        default: src = s2; dst = s2T; logK = 9; N = 128; break;
    }
    if (tr) total = N << logK;
    for (int e = blockIdx.x * 256 + threadIdx.x; e < total; e += 64 * 256) {
        float v;
        if (tr) {
            int n = e >> logK, k = e & ((1 << logK) - 1);
            v = src[(size_t)k * N + n];
        } else {
            v = src[e];
        }
        dst[e] = f2bf(v);
    }
}

// ---------------------------------------------------------------------------
// Pair-bias scatter into banded buffer band[i][h][jo], jo = j-i+16
// ---------------------------------------------------------------------------
__global__ __launch_bounds__(256) void k_scatter(
    const float* __restrict__ p_lm, const float* __restrict__ pair_w,
    const float* __restrict__ pair_b, const int* __restrict__ idx,
    float* __restrict__ band)
{
    int p = blockIdx.x * 256 + threadIdx.x;
    if (p >= PP) return;
    int i = idx[2 * p], j = idx[2 * p + 1];
    int d = j - i + WIN;
    if (d < 0 || d > 2 * WIN) return;
    float v0 = pair_b[0], v1 = pair_b[1], v2 = pair_b[2], v3 = pair_b[3];
    #pragma unroll
    for (int k = 0; k < 16; ++k) {
        float a = p_lm[p * 16 + k];
        v0 = fmaf(a, pair_w[k * 4 + 0], v0);
        v1 = fmaf(a, pair_w[k * 4 + 1], v1);
        v2 = fmaf(a, pair_w[k * 4 + 2], v2);
        v3 = fmaf(a, pair_w[k * 4 + 3], v3);
    }
    size_t base = ((size_t)i * HH) * BAND + d;
    band[base + 0 * BAND] = v0;
    band[base + 1 * BAND] = v1;
    band[base + 2 * BAND] = v2;
    band[base + 3 * BAND] = v3;
}

// ---------------------------------------------------------------------------
// MFMA GEMM core: 16x16x32 bf16. Wave computes 16 rows x NF*16 cols.
// Arow  = per-lane A row pointer (row = m0 + w*16 + (lane&15))
// WTcol = per-lane WT col pointer (col = n0 + (lane&15)), WT layout [N][K]
// ko    = (lane>>4)*8
// ---------------------------------------------------------------------------
template<int K, int NF>
__device__ __forceinline__ void gemm_core(
    const ushort* __restrict__ Arow, const ushort* __restrict__ WTcol,
    f32x4* acc, int ko)
{
    #pragma unroll
    for (int ks = 0; ks < K / 32; ++ks) {
        bf16x8 a = *(const bf16x8*)(Arow + ks * 32 + ko);
        #pragma unroll
        for (int nf = 0; nf < NF; ++nf) {
            bf16x8 b = *(const bf16x8*)(WTcol + (size_t)nf * 16 * K + ks * 32 + ko);
            acc[nf] = __builtin_amdgcn_mfma_f32_16x16x32_bf16(a, b, acc[nf], 0, 0, 0);
        }
    }
}

// ---------------------------------------------------------------------------
// cond_bf = bf16( gather(h_cond,tok) @ cond_w + t_emb + cond_b )
// grid (64, 4): M-tile 64, N-tile 32. K=512.
// ---------------------------------------------------------------------------
__global__ __launch_bounds__(256) void k_cond(
    const ushort* __restrict__ hcb, const int* __restrict__ tok,
    const ushort* __restrict__ cwT, const float* __restrict__ t_emb,
    const float* __restrict__ cond_b, ushort* __restrict__ cond_bf)
{
    const int tid = threadIdx.x, l = tid & 63, w = tid >> 6;
    const int cl = l & 15, ko = (l >> 4) * 8;
    const int m0 = blockIdx.x * 64, n0 = blockIdx.y * 32;
    const int trow = tok[m0 + w * 16 + cl];
    f32x4 acc[2] = {};
    gemm_core<512, 2>(hcb + (size_t)trow * DM, cwT + (size_t)(n0 + cl) * DM, acc, ko);
    const int r0 = m0 + w * 16 + (l >> 4) * 4;
    #pragma unroll
    for (int nf = 0; nf < 2; ++nf) {
        int col = n0 + nf * 16 + cl;
        float add = t_emb[col] + cond_b[col];
        #pragma unroll
        for (int r = 0; r < 4; ++r)
            cond_bf[(size_t)(r0 + r) * DA + col] = f2bf(acc[nf][r] + add);
    }
}

// ---------------------------------------------------------------------------
// gb{1,2} = cond @ adaln{1,2}_w + b.  grid (64, 4, 2). K=128, N=256, BN=64.
// ---------------------------------------------------------------------------
__global__ __launch_bounds__(256) void k_ada(
    const ushort* __restrict__ cond_bf,
    const ushort* __restrict__ a1T, const ushort* __restrict__ a2T,
    const float* __restrict__ b1, const float* __restrict__ b2,
    float* __restrict__ gb1, float* __restrict__ gb2)
{
    const int tid = threadIdx.x, l = tid & 63, w = tid >> 6;
    const int cl = l & 15, ko = (l >> 4) * 8;
    const int m0 = blockIdx.x * 64, n0 = blockIdx.y * 64;
    const ushort* WT = blockIdx.z ? a2T : a1T;
    const float* bias = blockIdx.z ? b2 : b1;
    float* O = blockIdx.z ? gb2 : gb1;
    f32x4 acc[4] = {};
    gemm_core<128, 4>(cond_bf + (size_t)(m0 + w * 16 + cl) * DA,
                      WT + (size_t)(n0 + cl) * DA, acc, ko);
    const int r0 = m0 + w * 16 + (l >> 4) * 4;
    #pragma unroll
    for (int nf = 0; nf < 4; ++nf) {
        int col = n0 + nf * 16 + cl;
        float bb = bias[col];
        #pragma unroll
        for (int r = 0; r < 4; ++r)
            O[(size_t)(r0 + r) * 256 + col] = acc[nf][r] + bb;
    }
}

// ---------------------------------------------------------------------------
// gate{1,2} = sigmoid(c_atom @ g{1,2}w + b). grid (64, 2, 2). K=128, N=128.
// ---------------------------------------------------------------------------
__global__ __launch_bounds__(256) void k_gate(
    const ushort* __restrict__ cab,
    const ushort* __restrict__ g1T, const ushort* __restrict__ g2T,
    const float* __restrict__ b1, const float* __restrict__ b2,
    float* __restrict__ gate1, float* __restrict__ gate2)
{
    const int tid = threadIdx.x, l = tid & 63, w = tid >> 6;
    const int cl = l & 15, ko = (l >> 4) * 8;
    const int m0 = blockIdx.x * 64, n0 = blockIdx.y * 64;
    const ushort* WT = blockIdx.z ? g2T : g1T;
    const float* bias = blockIdx.z ? b2 : b1;
    float* O = blockIdx.z ? gate2 : gate1;
    f32x4 acc[4] = {};
    gemm_core<128, 4>(cab + (size_t)(m0 + w * 16 + cl) * DA,
                      WT + (size_t)(n0 + cl) * DA, acc, ko);
    const int r0 = m0 + w * 16 + (l >> 4) * 4;
    #pragma unroll
    for (int nf = 0; nf < 4; ++nf) {
        int col = n0 + nf * 16 + cl;
        float bb = bias[col];
        #pragma unroll
        for (int r = 0; r < 4; ++r)
            O[(size_t)(r0 + r) * DA + col] = sigmoidf_(acc[nf][r] + bb);
    }
}

// ---------------------------------------------------------------------------
// LN + adaLN modulate -> bf16. AFFINE: ln_g/ln_b applied (layer 1).
// Block = 4 waves = 4 rows. grid 1024.
// ---------------------------------------------------------------------------
template<int AFFINE>
__global__ __launch_bounds__(256) void k_ln(
    const float* __restrict__ x, const float* __restrict__ gb,
    const float* __restrict__ ln_g, const float* __restrict__ ln_b,
    ushort* __restrict__ out_bf)
{
    const int w = threadIdx.x >> 6, l = threadIdx.x & 63;
    const int row = blockIdx.x * 4 + w;
    float2 xv = *(const float2*)&x[(size_t)row * DA + 2 * l];
    float sum = xv.x + xv.y, sq = xv.x * xv.x + xv.y * xv.y;
    #pragma unroll
    for (int off = 1; off <= 32; off <<= 1) {
        sum += __shfl_xor(sum, off);
        sq  += __shfl_xor(sq,  off);
    }
    float m = sum * (1.0f / DA);
    float var = sq * (1.0f / DA) - m * m;
    float rs = rsqrtf(var + 1e-5f);
    float2 g = *(const float2*)&gb[(size_t)row * 256 + 2 * l];
    float2 b = *(const float2*)&gb[(size_t)row * 256 + 128 + 2 * l];
    float xn0 = (xv.x - m) * rs, xn1 = (xv.y - m) * rs;
    if (AFFINE) {
        float2 lg = *(const float2*)&ln_g[2 * l];
        float2 lb = *(const float2*)&ln_b[2 * l];
        xn0 = xn0 * lg.x + lb.x;
        xn1 = xn1 * lg.y + lb.y;
    }
    ushort2 st;
    st.x = f2bf((1.f + g.x) * xn0 + b.x);
    st.y = f2bf((1.f + g.y) * xn1 + b.y);
    *(ushort2*)&out_bf[(size_t)row * DA + 2 * l] = st;
}

// ---------------------------------------------------------------------------
// Q,K,V,sigmoid(G) = qn @ {wq,wk,wv,wg}. grid (64, 2, 4). K=128, BN=64.
// ---------------------------------------------------------------------------
__global__ __launch_bounds__(256) void k_qkvg(
    const ushort* __restrict__ qn_bf,
    const ushort* __restrict__ wqT, const ushort* __restrict__ wkT,
    const ushort* __restrict__ wvT, const ushort* __restrict__ wgT,
    float* __restrict__ Qb, float* __restrict__ Kb,
    float* __restrict__ Vb, float* __restrict__ sG)
{
    const int tid = threadIdx.x, l = tid & 63, w = tid >> 6;
    const int cl = l & 15, ko = (l >> 4) * 8;
    const int m0 = blockIdx.x * 64, n0 = blockIdx.y * 64;
    const int z = blockIdx.z;
    const ushort* WT = (z == 0) ? wqT : (z == 1) ? wkT : (z == 2) ? wvT : wgT;
    float* O = (z == 0) ? Qb : (z == 1) ? Kb : (z == 2) ? Vb : sG;
    f32x4 acc[4] = {};
    gemm_core<128, 4>(qn_bf + (size_t)(m0 + w * 16 + cl) * DA,
                      WT + (size_t)(n0 + cl) * DA, acc, ko);
    const int r0 = m0 + w * 16 + (l >> 4) * 4;
    #pragma unroll
    for (int nf = 0; nf < 4; ++nf) {
        int col = n0 + nf * 16 + cl;
        #pragma unroll
        for (int r = 0; r < 4; ++r) {
            float v = acc[nf][r];
            if (z == 3) v = sigmoidf_(v);
            O[(size_t)(r0 + r) * DA + col] = v;
        }
    }
}

// ---------------------------------------------------------------------------
// Banded attention (f32): 8 lanes per (i,h), lane owns 4 dims. -> att_bf
// ---------------------------------------------------------------------------
__global__ __launch_bounds__(256) void k_attn(
    const float* __restrict__ Qb, const float* __restrict__ Kb,
    const float* __restrict__ Vb, const float* __restrict__ band,
    ushort* __restrict__ att_bf)
{
    const int tid = threadIdx.x;
    const int g = tid >> 3, l = tid & 7;
    const int i = blockIdx.x * 8 + (g >> 2), h = g & 3;
    const float scale = 0.17677669529663687f;   // 1/sqrt(32)
    float4 qr = *(const float4*)(Qb + (size_t)i * DA + h * 32 + l * 4);
    const float* brow = band + ((size_t)i * HH + h) * BAND;

    float s[BAND];
    float m = -1e30f;
    #pragma unroll
    for (int jo = 0; jo < BAND; ++jo) {
        int j = i - WIN + jo;
        float sv = -1e30f;
        if ((unsigned)j < NA) {
            float4 kk = *(const float4*)(Kb + (size_t)j * DA + h * 32 + l * 4);
            float d = 0.f;
            d = fmaf(qr.x, kk.x, d); d = fmaf(qr.y, kk.y, d);
            d = fmaf(qr.z, kk.z, d); d = fmaf(qr.w, kk.w, d);
            d += __shfl_xor(d, 1);
            d += __shfl_xor(d, 2);
            d += __shfl_xor(d, 4);
            sv = fmaf(d, scale, brow[jo]);
        }
        s[jo] = sv;
        m = fmaxf(m, sv);
    }
    float lsum = 0.f;
    #pragma unroll
    for (int jo = 0; jo < BAND; ++jo) {
        float p = __expf(s[jo] - m);
        s[jo] = p;
        lsum += p;
    }
    float inv = 1.0f / lsum;
    float4 o = {0.f, 0.f, 0.f, 0.f};
    #pragma unroll
    for (int jo = 0; jo < BAND; ++jo) {
        int j = i - WIN + jo;
        if ((unsigned)j < NA) {
            float4 v = *(const float4*)(Vb + (size_t)j * DA + h * 32 + l * 4);
            o.x = fmaf(s[jo], v.x, o.x);
            o.y = fmaf(s[jo], v.y, o.y);
            o.z = fmaf(s[jo], v.z, o.z);
            o.w = fmaf(s[jo], v.w, o.w);
        }
    }
    ushort4 st;
    st.x = f2bf(o.x * inv); st.y = f2bf(o.y * inv);
    st.z = f2bf(o.z * inv); st.w = f2bf(o.w * inv);
    *(ushort4*)&att_bf[(size_t)i * DA + h * 32 + l * 4] = st;
}

// ---------------------------------------------------------------------------
// q1 = (q + sG * (att @ wo)) * (1 + gate1). grid (64, 4). K=128, BN=32.
// ---------------------------------------------------------------------------
__global__ __launch_bounds__(256) void k_wo(
    const ushort* __restrict__ att_bf, const ushort* __restrict__ woT,
    const float* __restrict__ q, const float* __restrict__ sG,
    const float* __restrict__ gate1, float* __restrict__ q1)
{
    const int tid = threadIdx.x, l = tid & 63, w = tid >> 6;
    const int cl = l & 15, ko = (l >> 4) * 8;
    const int m0 = blockIdx.x * 64, n0 = blockIdx.y * 32;
    f32x4 acc[2] = {};
    gemm_core<128, 2>(att_bf + (size_t)(m0 + w * 16 + cl) * DA,
                      woT + (size_t)(n0 + cl) * DA, acc, ko);
    const int r0 = m0 + w * 16 + (l >> 4) * 4;
    #pragma unroll
    for (int nf = 0; nf < 2; ++nf) {
        int col = n0 + nf * 16 + cl;
        #pragma unroll
        for (int r = 0; r < 4; ++r) {
            size_t rc = (size_t)(r0 + r) * DA + col;
            q1[rc] = (q[rc] + sG[rc] * acc[nf][r]) * (1.f + gate1[rc]);
        }
    }
}

// ---------------------------------------------------------------------------
// hb = bf16( silu(qn2 @ sw1) * (qn2 @ sw3) ). grid (64, 8). K=128, BN=64 dual.
// ---------------------------------------------------------------------------
__global__ __launch_bounds__(256) void k_sw13(
    const ushort* __restrict__ qn2_bf,
    const ushort* __restrict__ s1T, const ushort* __restrict__ s3T,
    ushort* __restrict__ hb_bf)
{
    const int tid = threadIdx.x, l = tid & 63, w = tid >> 6;
    const int cl = l & 15, ko = (l >> 4) * 8;
    const int m0 = blockIdx.x * 64, n0 = blockIdx.y * 64;
    const ushort* Arow = qn2_bf + (size_t)(m0 + w * 16 + cl) * DA;
    const ushort* W1 = s1T + (size_t)(n0 + cl) * DA;
    const ushort* W3 = s3T + (size_t)(n0 + cl) * DA;
    f32x4 acc1[4] = {}, acc3[4] = {};
    #pragma unroll
    for (int ks = 0; ks < 4; ++ks) {
        bf16x8 a = *(const bf16x8*)(Arow + ks * 32 + ko);
        #pragma unroll
        for (int nf = 0; nf < 4; ++nf) {
            bf16x8 b1 = *(const bf16x8*)(W1 + (size_t)nf * 16 * DA + ks * 32 + ko);
            acc1[nf] = __builtin_amdgcn_mfma_f32_16x16x32_bf16(a, b1, acc1[nf], 0, 0, 0);
            bf16x8 b3 = *(const bf16x8*)(W3 + (size_t)nf * 16 * DA + ks * 32 + ko);
            acc3[nf] = __builtin_amdgcn_mfma_f32_16x16x32_bf16(a, b3, acc3[nf], 0, 0, 0);
        }
    }
    const int r0 = m0 + w * 16 + (l >> 4) * 4;
    #pragma unroll
    for (int nf = 0; nf < 4; ++nf) {
        int col = n0 + nf * 16 + cl;
        #pragma unroll
        for (int r = 0; r < 4; ++r) {
            float x1 = acc1[nf][r], x3 = acc3[nf][r];
            hb_bf[(size_t)(r0 + r) * DF + col] = f2bf(x1 * sigmoidf_(x1) * x3);
        }
    }
}

// ---------------------------------------------------------------------------
// out = q1 + gate2 * (hb @ sw2). grid (64, 4). K=512, BN=32.
// ---------------------------------------------------------------------------
__global__ __launch_bounds__(256) void k_sw2(
    const ushort* __restrict__ hb_bf, const ushort* __restrict__ s2T,
    const float* __restrict__ q1, const float* __restrict__ gate2,
    float* __restrict__ out)
{
    const int tid = threadIdx.x, l = tid & 63, w = tid >> 6;
    const int cl = l & 15, ko = (l >> 4) * 8;
    const int m0 = blockIdx.x * 64, n0 = blockIdx.y * 32;
    f32x4 acc[2] = {};
    gemm_core<512, 2>(hb_bf + (size_t)(m0 + w * 16 + cl) * DF,
                      s2T + (size_t)(n0 + cl) * DF, acc, ko);
    const int r0 = m0 + w * 16 + (l >> 4) * 4;
    #pragma unroll
    for (int nf = 0; nf < 2; ++nf) {
        int col = n0 + nf * 16 + cl;
        #pragma unroll
        for (int r = 0; r < 4; ++r) {
            size_t rc = (size_t)(r0 + r) * DA + col;
            out[rc] = q1[rc] + gate2[rc] * acc[nf][r];
        }
    }
}

// ---------------------------------------------------------------------------
extern "C" void kernel_launch(void* const* d_in, const int* in_sizes, int n_in,
                              void* d_out, int out_size, void* d_ws, size_t ws_size,
                              hipStream_t stream)
{
    const float* q      = (const float*)d_in[0];
    const float* c_atom = (const float*)d_in[1];
    const float* h_cond = (const float*)d_in[2];
    const float* p_lm   = (const float*)d_in[3];
    const float* t_emb  = (const float*)d_in[4];
    const float* cond_w = (const float*)d_in[5];
    const float* cond_b = (const float*)d_in[6];
    const float* ad1w   = (const float*)d_in[7];
    const float* ad1b   = (const float*)d_in[8];
    const float* ad2w   = (const float*)d_in[9];
    const float* ad2b   = (const float*)d_in[10];
    const float* ln_g   = (const float*)d_in[11];
    const float* ln_b   = (const float*)d_in[12];
    const float* wq     = (const float*)d_in[13];
    const float* wk     = (const float*)d_in[14];
    const float* wv     = (const float*)d_in[15];
    const float* wg     = (const float*)d_in[16];
    const float* wo     = (const float*)d_in[17];
    const float* pair_w = (const float*)d_in[18];
    const float* pair_b = (const float*)d_in[19];
    const float* g1w    = (const float*)d_in[20];
    const float* g1b    = (const float*)d_in[21];
    const float* g2w    = (const float*)d_in[22];
    const float* g2b    = (const float*)d_in[23];
    const float* sw1    = (const float*)d_in[24];
    const float* sw3    = (const float*)d_in[25];
    const float* sw2    = (const float*)d_in[26];
    const int*   p_idx  = (const int*)d_in[27];
    const int*   tok    = (const int*)d_in[28];
    float* out = (float*)d_out;

    size_t off = 0;
    char* base = (char*)d_ws;
    auto alloc = [&](size_t bytes) -> void* {
        void* p = base + off;
        off += (bytes + 255) & ~(size_t)255;
        return p;
    };
    ushort* hcb     = (ushort*)alloc((size_t)NT * DM * 2);
    ushort* cab     = (ushort*)alloc((size_t)NA * DA * 2);
    ushort* cwT     = (ushort*)alloc((size_t)DM * DA * 2);
    ushort* a1T     = (ushort*)alloc((size_t)256 * 128 * 2);
    ushort* a2T     = (ushort*)alloc((size_t)256 * 128 * 2);
    ushort* wqT     = (ushort*)alloc((size_t)128 * 128 * 2);
    ushort* wkT     = (ushort*)alloc((size_t)128 * 128 * 2);
    ushort* wvT     = (ushort*)alloc((size_t)128 * 128 * 2);
    ushort* wgT     = (ushort*)alloc((size_t)128 * 128 * 2);
    ushort* woT     = (ushort*)alloc((size_t)128 * 128 * 2);
    ushort* g1T     = (ushort*)alloc((size_t)128 * 128 * 2);
    ushort* g2T     = (ushort*)alloc((size_t)128 * 128 * 2);
    ushort* s1T     = (ushort*)alloc((size_t)512 * 128 * 2);
    ushort* s3T     = (ushort*)alloc((size_t)512 * 128 * 2);
    ushort* s2T     = (ushort*)alloc((size_t)128 * 512 * 2);
    ushort* cond_bf = (ushort*)alloc((size_t)NA * DA * 2);
    float*  gb1     = (float*)alloc((size_t)NA * 256 * 4);
    float*  gb2     = (float*)alloc((size_t)NA * 256 * 4);
    float*  gate1   = (float*)alloc((size_t)NA * DA * 4);
    float*  gate2   = (float*)alloc((size_t)NA * DA * 4);
    ushort* qn_bf   = (ushort*)alloc((size_t)NA * DA * 2);
    float*  Qb      = (float*)alloc((size_t)NA * DA * 4);
    float*  Kb      = (float*)alloc((size_t)NA * DA * 4);
    float*  Vb      = (float*)alloc((size_t)NA * DA * 4);
    float*  sG      = (float*)alloc((size_t)NA * DA * 4);
    float*  band    = (float*)alloc((size_t)NA * HH * BAND * 4);
    ushort* att_bf  = (ushort*)alloc((size_t)NA * DA * 2);
    float*  q1      = (float*)alloc((size_t)NA * DA * 4);
    ushort* qn2_bf  = (ushort*)alloc((size_t)NA * DA * 2);
    ushort* hb_bf   = (ushort*)alloc((size_t)NA * DF * 2);

    k_prep<<<dim3(64, 15), 256, 0, stream>>>(
        h_cond, c_atom, cond_w, ad1w, ad2w, wq, wk, wv, wg, wo,
        g1w, g2w, sw1, sw3, sw2,
        hcb, cab, cwT, a1T, a2T, wqT, wkT, wvT, wgT, woT,
        g1T, g2T, s1T, s3T, s2T);
    hipMemsetAsync(band, 0, (size_t)NA * HH * BAND * sizeof(float), stream);
    k_scatter<<<PP / 256, 256, 0, stream>>>(p_lm, pair_w, pair_b, p_idx, band);
    k_cond<<<dim3(64, 4), 256, 0, stream>>>(hcb, tok, cwT, t_emb, cond_b, cond_bf);
    k_ada<<<dim3(64, 4, 2), 256, 0, stream>>>(cond_bf, a1T, a2T, ad1b, ad2b, gb1, gb2);
    k_gate<<<dim3(64, 2, 2), 256, 0, stream>>>(cab, g1T, g2T, g1b, g2b, gate1, gate2);
    k_ln<1><<<NA / 4, 256, 0, stream>>>(q, gb1, ln_g, ln_b, qn_bf);
    k_qkvg<<<dim3(64, 2, 4), 256, 0, stream>>>(qn_bf, wqT, wkT, wvT, wgT, Qb, Kb, Vb, sG);
    k_attn<<<NA / 8, 256, 0, stream>>>(Qb, Kb, Vb, band, att_bf);
    k_wo<<<dim3(64, 4), 256, 0, stream>>>(att_bf, woT, q, sG, gate1, q1);
    k_ln<0><<<NA / 4, 256, 0, stream>>>(q1, gb2, ln_g, ln_b, qn2_bf);
    k_sw13<<<dim3(64, 8), 256, 0, stream>>>(qn2_bf, s1T, s3T, hb_bf);
    k_sw2<<<dim3(64, 4), 256, 0, stream>>>(hb_bf, s2T, q1, gate2, out);
    (void)in_sizes; (void)n_in; (void)out_size; (void)ws_size;
}

// Round 5
// 198.770 us; speedup vs baseline: 1.8566x; 1.0389x over previous
//
#include <hip/hip_runtime.h>
#include <math.h>

#define NA   4096
#define DA   128
#define DM   512
#define NT   1024
#define HH   4
#define DF   512
#define PP   32768
#define WIN  16
#define BAND 33

typedef __attribute__((ext_vector_type(8))) short bf16x8;
typedef __attribute__((ext_vector_type(4))) float f32x4;

__device__ __forceinline__ float sigmoidf_(float x) { return 1.0f / (1.0f + __expf(-x)); }
__device__ __forceinline__ ushort f2bf(float f) {
    union { float f; unsigned int i; } x; x.f = f;
    unsigned int r = x.i + 0x7fffu + ((x.i >> 16) & 1u);
    return (ushort)(r >> 16);
}

// ---------------------------------------------------------------------------
// MFMA GEMM core: 16x16x32 bf16. Wave computes 16 rows x NF*16 cols.
// ---------------------------------------------------------------------------
template<int K, int NF>
__device__ __forceinline__ void gemm_core(
    const ushort* __restrict__ Arow, const ushort* __restrict__ WTcol,
    f32x4* acc, int ko)
{
    #pragma unroll
    for (int ks = 0; ks < K / 32; ++ks) {
        bf16x8 a = *(const bf16x8*)(Arow + ks * 32 + ko);
        #pragma unroll
        for (int nf = 0; nf < NF; ++nf) {
            bf16x8 b = *(const bf16x8*)(WTcol + (size_t)nf * 16 * K + ks * 32 + ko);
            acc[nf] = __builtin_amdgcn_mfma_f32_16x16x32_bf16(a, b, acc[nf], 0, 0, 0);
        }
    }
}

// ---------------------------------------------------------------------------
// Prep: bf16 weight transposes (coalesced via 32x32 LDS tile), activation
// converts, zero band, zero out.  grid (64, 17)
// ---------------------------------------------------------------------------
__global__ __launch_bounds__(256) void k_prep(
    const float* __restrict__ hc, const float* __restrict__ ca,
    const float* __restrict__ cw, const float* __restrict__ a1, const float* __restrict__ a2,
    const float* __restrict__ wq, const float* __restrict__ wk, const float* __restrict__ wv,
    const float* __restrict__ wg, const float* __restrict__ wo,
    const float* __restrict__ g1, const float* __restrict__ g2,
    const float* __restrict__ s1, const float* __restrict__ s3, const float* __restrict__ s2,
    ushort* hcb, ushort* cab, ushort* cwT, ushort* a1T, ushort* a2T,
    ushort* wqT, ushort* wkT, ushort* wvT, ushort* wgT, ushort* woT,
    ushort* g1T, ushort* g2T, ushort* s1T, ushort* s3T, ushort* s2T,
    float* band, float* outz)
{
    __shared__ float tile[32][33];
    const int y = blockIdx.y, bx = blockIdx.x, tid = threadIdx.x;
    if (y <= 1) {
        const float4* src = (const float4*)(y == 0 ? hc : ca);
        ushort* dst = y == 0 ? hcb : cab;
        for (int i = bx * 256 + tid; i < 131072; i += 16384) {
            float4 v = src[i];
            ushort4 st; st.x = f2bf(v.x); st.y = f2bf(v.y); st.z = f2bf(v.z); st.w = f2bf(v.w);
            *(ushort4*)&dst[(size_t)i * 4] = st;
        }
        return;
    }
    if (y == 15) {
        float4 z = {0.f, 0.f, 0.f, 0.f};
        float4* b4 = (float4*)band;
        for (int i = bx * 256 + tid; i < 135168; i += 16384) b4[i] = z;
        return;
    }
    if (y == 16) {
        float4 z = {0.f, 0.f, 0.f, 0.f};
        float4* o4 = (float4*)outz;
        for (int i = bx * 256 + tid; i < 131072; i += 16384) o4[i] = z;
        return;
    }
    const float* src; ushort* dst; int K, N;
    switch (y) {
        case 2:  src = cw; dst = cwT; K = 512; N = 128; break;
        case 3:  src = a1; dst = a1T; K = 128; N = 256; break;
        case 4:  src = a2; dst = a2T; K = 128; N = 256; break;
        case 5:  src = wq; dst = wqT; K = 128; N = 128; break;
        case 6:  src = wk; dst = wkT; K = 128; N = 128; break;
        case 7:  src = wv; dst = wvT; K = 128; N = 128; break;
        case 8:  src = wg; dst = wgT; K = 128; N = 128; break;
        case 9:  src = wo; dst = woT; K = 128; N = 128; break;
        case 10: src = g1; dst = g1T; K = 128; N = 128; break;
        case 11: src = g2; dst = g2T; K = 128; N = 128; break;
        case 12: src = s1; dst = s1T; K = 128; N = 512; break;
        case 13: src = s3; dst = s3T; K = 128; N = 512; break;
        default: src = s2; dst = s2T; K = 512; N = 128; break;
    }
    const int tn_cnt = N >> 5;
    if (bx >= (K >> 5) * tn_cnt) return;
    const int k0 = (bx / tn_cnt) << 5, n0 = (bx % tn_cnt) << 5;
    {
        int r = tid >> 3, c = (tid & 7) << 2;
        float4 v = *(const float4*)&src[(size_t)(k0 + r) * N + n0 + c];
        tile[r][c + 0] = v.x; tile[r][c + 1] = v.y;
        tile[r][c + 2] = v.z; tile[r][c + 3] = v.w;
    }
    __syncthreads();
    {
        int rn = tid >> 3, ck = (tid & 7) << 2;
        ushort4 st;
        st.x = f2bf(tile[ck + 0][rn]);
        st.y = f2bf(tile[ck + 1][rn]);
        st.z = f2bf(tile[ck + 2][rn]);
        st.w = f2bf(tile[ck + 3][rn]);
        *(ushort4*)&dst[(size_t)(n0 + rn) * K + k0 + ck] = st;
    }
}

// ---------------------------------------------------------------------------
// cond GEMM (y<4) + pair-bias scatter (y=4,5).  grid (64, 6)
// ---------------------------------------------------------------------------
__global__ __launch_bounds__(256) void k_cond(
    const ushort* __restrict__ hcb, const int* __restrict__ tok,
    const ushort* __restrict__ cwT, const float* __restrict__ t_emb,
    const float* __restrict__ cond_b, ushort* __restrict__ cond_bf,
    const float* __restrict__ p_lm, const float* __restrict__ pair_w,
    const float* __restrict__ pair_b, const int* __restrict__ p_idx,
    float* __restrict__ band)
{
    const int tid = threadIdx.x, y = blockIdx.y;
    if (y >= 4) {
        int p = ((y - 4) * 64 + blockIdx.x) * 256 + tid;   // covers PP exactly
        int i = p_idx[2 * p], j = p_idx[2 * p + 1];
        int d = j - i + WIN;
        if (d < 0 || d > 2 * WIN) return;
        float v0 = pair_b[0], v1 = pair_b[1], v2 = pair_b[2], v3 = pair_b[3];
        #pragma unroll
        for (int k = 0; k < 16; ++k) {
            float a = p_lm[p * 16 + k];
            v0 = fmaf(a, pair_w[k * 4 + 0], v0);
            v1 = fmaf(a, pair_w[k * 4 + 1], v1);
            v2 = fmaf(a, pair_w[k * 4 + 2], v2);
            v3 = fmaf(a, pair_w[k * 4 + 3], v3);
        }
        size_t base = ((size_t)i * HH) * BAND + d;
        band[base + 0 * BAND] = v0;
        band[base + 1 * BAND] = v1;
        band[base + 2 * BAND] = v2;
        band[base + 3 * BAND] = v3;
        return;
    }
    const int l = tid & 63, w = tid >> 6, cl = l & 15, ko = (l >> 4) * 8;
    const int m0 = blockIdx.x * 64, n0 = y * 32;
    const int trow = tok[m0 + w * 16 + cl];
    f32x4 acc[2] = {};
    gemm_core<512, 2>(hcb + (size_t)trow * DM, cwT + (size_t)(n0 + cl) * DM, acc, ko);
    const int r0 = m0 + w * 16 + (l >> 4) * 4;
    #pragma unroll
    for (int nf = 0; nf < 2; ++nf) {
        int col = n0 + nf * 16 + cl;
        float add = t_emb[col] + cond_b[col];
        #pragma unroll
        for (int r = 0; r < 4; ++r)
            cond_bf[(size_t)(r0 + r) * DA + col] = f2bf(acc[nf][r] + add);
    }
}

// ---------------------------------------------------------------------------
// gb1/gb2 (from cond_bf) and sigmoid gates (from c_atom).  grid (64, 12)
// ---------------------------------------------------------------------------
__global__ __launch_bounds__(256) void k_modgate(
    const ushort* __restrict__ cond_bf, const ushort* __restrict__ cab,
    const ushort* __restrict__ a1T, const ushort* __restrict__ a2T,
    const ushort* __restrict__ g1T, const ushort* __restrict__ g2T,
    const float* __restrict__ ad1b, const float* __restrict__ ad2b,
    const float* __restrict__ g1b, const float* __restrict__ g2b,
    float* __restrict__ gb1, float* __restrict__ gb2,
    float* __restrict__ gate1, float* __restrict__ gate2)
{
    const int tid = threadIdx.x, y = blockIdx.y;
    const int l = tid & 63, w = tid >> 6, cl = l & 15, ko = (l >> 4) * 8;
    const int m0 = blockIdx.x * 64;
    const ushort* A; const ushort* WT; const float* bias; float* O; int ldo, n0, sig;
    if (y < 4)       { A = cond_bf; WT = a1T; bias = ad1b; O = gb1;   ldo = 256; n0 = y * 64;        sig = 0; }
    else if (y < 8)  { A = cond_bf; WT = a2T; bias = ad2b; O = gb2;   ldo = 256; n0 = (y - 4) * 64;  sig = 0; }
    else if (y < 10) { A = cab;     WT = g1T; bias = g1b;  O = gate1; ldo = 128; n0 = (y - 8) * 64;  sig = 1; }
    else             { A = cab;     WT = g2T; bias = g2b;  O = gate2; ldo = 128; n0 = (y - 10) * 64; sig = 1; }
    f32x4 acc[4] = {};
    gemm_core<128, 4>(A + (size_t)(m0 + w * 16 + cl) * DA, WT + (size_t)(n0 + cl) * DA, acc, ko);
    const int r0 = m0 + w * 16 + (l >> 4) * 4;
    #pragma unroll
    for (int nf = 0; nf < 4; ++nf) {
        int col = n0 + nf * 16 + cl;
        float bb = bias[col];
        #pragma unroll
        for (int r = 0; r < 4; ++r) {
            float v = acc[nf][r] + bb;
            if (sig) v = sigmoidf_(v);
            O[(size_t)(r0 + r) * ldo + col] = v;
        }
    }
}

// ---------------------------------------------------------------------------
// In-register LN1 + adaLN modulate + QKVG MFMA.  grid (64, 2, 4)
// ---------------------------------------------------------------------------
__global__ __launch_bounds__(256) void k_qkvg(
    const float* __restrict__ q, const float* __restrict__ gb1,
    const float* __restrict__ ln_g, const float* __restrict__ ln_b,
    const ushort* __restrict__ wqT, const ushort* __restrict__ wkT,
    const ushort* __restrict__ wvT, const ushort* __restrict__ wgT,
    float* __restrict__ Qb, float* __restrict__ Kb,
    float* __restrict__ Vb, float* __restrict__ sG)
{
    const int tid = threadIdx.x, l = tid & 63, w = tid >> 6;
    const int cl = l & 15, kq = l >> 4, ko = kq * 8;
    const int m0 = blockIdx.x * 64, n0 = blockIdx.y * 64, z = blockIdx.z;
    const int row = m0 + w * 16 + cl;

    float qv[4][8];
    float sum = 0.f, sq = 0.f;
    #pragma unroll
    for (int ks = 0; ks < 4; ++ks) {
        float4 v0 = *(const float4*)&q[(size_t)row * DA + ks * 32 + ko];
        float4 v1 = *(const float4*)&q[(size_t)row * DA + ks * 32 + ko + 4];
        qv[ks][0] = v0.x; qv[ks][1] = v0.y; qv[ks][2] = v0.z; qv[ks][3] = v0.w;
        qv[ks][4] = v1.x; qv[ks][5] = v1.y; qv[ks][6] = v1.z; qv[ks][7] = v1.w;
        sum += v0.x + v0.y + v0.z + v0.w + v1.x + v1.y + v1.z + v1.w;
        sq += v0.x * v0.x + v0.y * v0.y + v0.z * v0.z + v0.w * v0.w
            + v1.x * v1.x + v1.y * v1.y + v1.z * v1.z + v1.w * v1.w;
    }
    sum += __shfl_xor(sum, 16); sq += __shfl_xor(sq, 16);
    sum += __shfl_xor(sum, 32); sq += __shfl_xor(sq, 32);
    float mean = sum * (1.0f / DA);
    float rs = rsqrtf(sq * (1.0f / DA) - mean * mean + 1e-5f);

    bf16x8 afr[4];
    #pragma unroll
    for (int ks = 0; ks < 4; ++ks) {
        int k = ks * 32 + ko;
        float4 lg0 = *(const float4*)&ln_g[k], lg1 = *(const float4*)&ln_g[k + 4];
        float4 lb0 = *(const float4*)&ln_b[k], lb1 = *(const float4*)&ln_b[k + 4];
        float4 g0 = *(const float4*)&gb1[(size_t)row * 256 + k];
        float4 g1v = *(const float4*)&gb1[(size_t)row * 256 + k + 4];
        float4 b0 = *(const float4*)&gb1[(size_t)row * 256 + 128 + k];
        float4 b1v = *(const float4*)&gb1[(size_t)row * 256 + 128 + k + 4];
        float lg[8] = {lg0.x, lg0.y, lg0.z, lg0.w, lg1.x, lg1.y, lg1.z, lg1.w};
        float lb[8] = {lb0.x, lb0.y, lb0.z, lb0.w, lb1.x, lb1.y, lb1.z, lb1.w};
        float gg[8] = {g0.x, g0.y, g0.z, g0.w, g1v.x, g1v.y, g1v.z, g1v.w};
        float bb[8] = {b0.x, b0.y, b0.z, b0.w, b1v.x, b1v.y, b1v.z, b1v.w};
        #pragma unroll
        for (int j = 0; j < 8; ++j) {
            float xn = (qv[ks][j] - mean) * rs;
            float yv = (1.f + gg[j]) * (xn * lg[j] + lb[j]) + bb[j];
            afr[ks][j] = (short)f2bf(yv);
        }
    }

    const ushort* WT = (z == 0) ? wqT : (z == 1) ? wkT : (z == 2) ? wvT : wgT;
    float* O = (z == 0) ? Qb : (z == 1) ? Kb : (z == 2) ? Vb : sG;
    const ushort* Wc = WT + (size_t)(n0 + cl) * DA;
    f32x4 acc[4] = {};
    #pragma unroll
    for (int ks = 0; ks < 4; ++ks) {
        #pragma unroll
        for (int nf = 0; nf < 4; ++nf) {
            bf16x8 b = *(const bf16x8*)(Wc + (size_t)nf * 16 * DA + ks * 32 + ko);
            acc[nf] = __builtin_amdgcn_mfma_f32_16x16x32_bf16(afr[ks], b, acc[nf], 0, 0, 0);
        }
    }
    const int r0 = m0 + w * 16 + kq * 4;
    #pragma unroll
    for (int nf = 0; nf < 4; ++nf) {
        int col = n0 + nf * 16 + cl;
        #pragma unroll
        for (int r = 0; r < 4; ++r) {
            float v = acc[nf][r];
            if (z == 3) v = sigmoidf_(v);
            O[(size_t)(r0 + r) * DA + col] = v;
        }
    }
}

// ---------------------------------------------------------------------------
// Fused banded attention (f32) + wo MFMA + gated residual.  grid 256, 512 thr.
// ---------------------------------------------------------------------------
__global__ __launch_bounds__(512) void k_attnwo(
    const float* __restrict__ Qb, const float* __restrict__ Kb,
    const float* __restrict__ Vb, const float* __restrict__ band,
    const float* __restrict__ q, const float* __restrict__ sG,
    const float* __restrict__ gate1, const ushort* __restrict__ woT,
    float* __restrict__ q1)
{
    __shared__ ushort att_s[16 * 128];
    const int tid = threadIdx.x;
    const int r0 = blockIdx.x * 16;
    {
        const int g = tid >> 3, l3 = tid & 7;
        const int rl = g >> 2, h = g & 3;
        const int i = r0 + rl;
        const float scale = 0.17677669529663687f;   // 1/sqrt(32)
        float4 qr = *(const float4*)(Qb + (size_t)i * DA + h * 32 + l3 * 4);
        const float* brow = band + ((size_t)i * HH + h) * BAND;
        float s[BAND];
        float m = -1e30f;
        #pragma unroll
        for (int jo = 0; jo < BAND; ++jo) {
            int j = i - WIN + jo;
            float sv = -1e30f;
            if ((unsigned)j < NA) {
                float4 kk = *(const float4*)(Kb + (size_t)j * DA + h * 32 + l3 * 4);
                float d = 0.f;
                d = fmaf(qr.x, kk.x, d); d = fmaf(qr.y, kk.y, d);
                d = fmaf(qr.z, kk.z, d); d = fmaf(qr.w, kk.w, d);
                d += __shfl_xor(d, 1);
                d += __shfl_xor(d, 2);
                d += __shfl_xor(d, 4);
                sv = fmaf(d, scale, brow[jo]);
            }
            s[jo] = sv;
            m = fmaxf(m, sv);
        }
        float lsum = 0.f;
        #pragma unroll
        for (int jo = 0; jo < BAND; ++jo) {
            float p = __expf(s[jo] - m);
            s[jo] = p;
            lsum += p;
        }
        float inv = 1.0f / lsum;
        float4 o = {0.f, 0.f, 0.f, 0.f};
        #pragma unroll
        for (int jo = 0; jo < BAND; ++jo) {
            int j = i - WIN + jo;
            if ((unsigned)j < NA) {
                float4 v = *(const float4*)(Vb + (size_t)j * DA + h * 32 + l3 * 4);
                o.x = fmaf(s[jo], v.x, o.x);
                o.y = fmaf(s[jo], v.y, o.y);
                o.z = fmaf(s[jo], v.z, o.z);
                o.w = fmaf(s[jo], v.w, o.w);
            }
        }
        ushort4 st;
        st.x = f2bf(o.x * inv); st.y = f2bf(o.y * inv);
        st.z = f2bf(o.z * inv); st.w = f2bf(o.w * inv);
        int byte = rl * 256 + h * 64 + l3 * 8;
        byte ^= (rl & 7) << 4;
        *(ushort4*)((char*)att_s + byte) = st;
    }
    __syncthreads();
    {
        const int l = tid & 63, w = tid >> 6;      // 8 waves, 16 cols each
        const int cl = l & 15, kq = l >> 4, ko = kq * 8;
        const int n0 = w * 16;
        f32x4 acc = {0.f, 0.f, 0.f, 0.f};
        #pragma unroll
        for (int ks = 0; ks < 4; ++ks) {
            int byteA = cl * 256 + (ks * 32 + ko) * 2;
            byteA ^= (cl & 7) << 4;
            bf16x8 a = *(const bf16x8*)((char*)att_s + byteA);
            bf16x8 b = *(const bf16x8*)(woT + (size_t)(n0 + cl) * DA + ks * 32 + ko);
            acc = __builtin_amdgcn_mfma_f32_16x16x32_bf16(a, b, acc, 0, 0, 0);
        }
        #pragma unroll
        for (int r = 0; r < 4; ++r) {
            int row = r0 + kq * 4 + r, col = n0 + cl;
            size_t rc = (size_t)row * DA + col;
            q1[rc] = (q[rc] + sG[rc] * acc[r]) * (1.f + gate1[rc]);
        }
    }
}

// ---------------------------------------------------------------------------
// Fused FFN: in-reg LN2 + sw1/sw3 MFMA -> LDS hb chunk -> split-K sw2 partial
// accumulated with atomicAdd into out.  grid (256, 4), 256 thr, 16-row blocks.
// ---------------------------------------------------------------------------
__global__ __launch_bounds__(256) void k_ffn(
    const float* __restrict__ q1, const float* __restrict__ gb2,
    const float* __restrict__ gate2,
    const ushort* __restrict__ s1T, const ushort* __restrict__ s3T,
    const ushort* __restrict__ s2T, float* __restrict__ out)
{
    __shared__ ushort hbs[16 * 128];
    const int tid = threadIdx.x, l = tid & 63, w = tid >> 6;
    const int cl = l & 15, kq = l >> 4, ko = kq * 8;
    const int m0 = blockIdx.x * 16;
    const int by = blockIdx.y;                  // hb col chunk == sw2 K chunk
    const int row = m0 + cl;

    float qv[4][8];
    float sum = 0.f, sq = 0.f;
    #pragma unroll
    for (int ks = 0; ks < 4; ++ks) {
        float4 v0 = *(const float4*)&q1[(size_t)row * DA + ks * 32 + ko];
        float4 v1 = *(const float4*)&q1[(size_t)row * DA + ks * 32 + ko + 4];
        qv[ks][0] = v0.x; qv[ks][1] = v0.y; qv[ks][2] = v0.z; qv[ks][3] = v0.w;
        qv[ks][4] = v1.x; qv[ks][5] = v1.y; qv[ks][6] = v1.z; qv[ks][7] = v1.w;
        sum += v0.x + v0.y + v0.z + v0.w + v1.x + v1.y + v1.z + v1.w;
        sq += v0.x * v0.x + v0.y * v0.y + v0.z * v0.z + v0.w * v0.w
            + v1.x * v1.x + v1.y * v1.y + v1.z * v1.z + v1.w * v1.w;
    }
    sum += __shfl_xor(sum, 16); sq += __shfl_xor(sq, 16);
    sum += __shfl_xor(sum, 32); sq += __shfl_xor(sq, 32);
    float mean = sum * (1.0f / DA);
    float rs = rsqrtf(sq * (1.0f / DA) - mean * mean + 1e-5f);

    bf16x8 afr[4];
    #pragma unroll
    for (int ks = 0; ks < 4; ++ks) {
        int k = ks * 32 + ko;
        float4 g0 = *(const float4*)&gb2[(size_t)row * 256 + k];
        float4 g1v = *(const float4*)&gb2[(size_t)row * 256 + k + 4];
        float4 b0 = *(const float4*)&gb2[(size_t)row * 256 + 128 + k];
        float4 b1v = *(const float4*)&gb2[(size_t)row * 256 + 128 + k + 4];
        float gg[8] = {g0.x, g0.y, g0.z, g0.w, g1v.x, g1v.y, g1v.z, g1v.w};
        float bb[8] = {b0.x, b0.y, b0.z, b0.w, b1v.x, b1v.y, b1v.z, b1v.w};
        #pragma unroll
        for (int j = 0; j < 8; ++j) {
            float xn = (qv[ks][j] - mean) * rs;
            afr[ks][j] = (short)f2bf((1.f + gg[j]) * xn + bb[j]);
        }
    }

    // sw1/sw3: this wave's hb cols = by*128 + w*32 + nf*16 + cl
    {
        const ushort* W1 = s1T + (size_t)(by * 128 + w * 32 + cl) * DA;
        const ushort* W3 = s3T + (size_t)(by * 128 + w * 32 + cl) * DA;
        f32x4 acc1[2] = {}, acc3[2] = {};
        #pragma unroll
        for (int ks = 0; ks < 4; ++ks) {
            #pragma unroll
            for (int nf = 0; nf < 2; ++nf) {
                bf16x8 b1 = *(const bf16x8*)(W1 + (size_t)nf * 16 * DA + ks * 32 + ko);
                acc1[nf] = __builtin_amdgcn_mfma_f32_16x16x32_bf16(afr[ks], b1, acc1[nf], 0, 0, 0);
                bf16x8 b3 = *(const bf16x8*)(W3 + (size_t)nf * 16 * DA + ks * 32 + ko);
                acc3[nf] = __builtin_amdgcn_mfma_f32_16x16x32_bf16(afr[ks], b3, acc3[nf], 0, 0, 0);
            }
        }
        #pragma unroll
        for (int nf = 0; nf < 2; ++nf) {
            #pragma unroll
            for (int r = 0; r < 4; ++r) {
                float x1 = acc1[nf][r], x3 = acc3[nf][r];
                float h = x1 * sigmoidf_(x1) * x3;
                int rr = kq * 4 + r;
                int col = w * 32 + nf * 16 + cl;
                int byte = rr * 256 + col * 2;
                byte ^= (rr & 7) << 4;
                *(ushort*)((char*)hbs + byte) = f2bf(h);
            }
        }
    }
    __syncthreads();
    // sw2 partial: wave w -> out cols w*32..+31, K = this 128-chunk of hb
    {
        const ushort* W2 = s2T + (size_t)(w * 32 + cl) * DF + by * 128;
        f32x4 acc[2] = {};
        #pragma unroll
        for (int ks = 0; ks < 4; ++ks) {
            int byteA = cl * 256 + (ks * 32 + ko) * 2;
            byteA ^= (cl & 7) << 4;
            bf16x8 a = *(const bf16x8*)((char*)hbs + byteA);
            #pragma unroll
            for (int nf = 0; nf < 2; ++nf) {
                bf16x8 b = *(const bf16x8*)(W2 + (size_t)nf * 16 * DF + ks * 32 + ko);
                acc[nf] = __builtin_amdgcn_mfma_f32_16x16x32_bf16(a, b, acc[nf], 0, 0, 0);
            }
        }
        #pragma unroll
        for (int nf = 0; nf < 2; ++nf) {
            #pragma unroll
            for (int r = 0; r < 4; ++r) {
                int rowg = m0 + kq * 4 + r, col = w * 32 + nf * 16 + cl;
                size_t rc = (size_t)rowg * DA + col;
                float val = gate2[rc] * acc[nf][r];
                if (by == 0) val += q1[rc];
                atomicAdd(&out[rc], val);
            }
        }
    }
}

// ---------------------------------------------------------------------------
extern "C" void kernel_launch(void* const* d_in, const int* in_sizes, int n_in,
                              void* d_out, int out_size, void* d_ws, size_t ws_size,
                              hipStream_t stream)
{
    const float* q      = (const float*)d_in[0];
    const float* c_atom = (const float*)d_in[1];
    const float* h_cond = (const float*)d_in[2];
    const float* p_lm   = (const float*)d_in[3];
    const float* t_emb  = (const float*)d_in[4];
    const float* cond_w = (const float*)d_in[5];
    const float* cond_b = (const float*)d_in[6];
    const float* ad1w   = (const float*)d_in[7];
    const float* ad1b   = (const float*)d_in[8];
    const float* ad2w   = (const float*)d_in[9];
    const float* ad2b   = (const float*)d_in[10];
    const float* ln_g   = (const float*)d_in[11];
    const float* ln_b   = (const float*)d_in[12];
    const float* wq     = (const float*)d_in[13];
    const float* wk     = (const float*)d_in[14];
    const float* wv     = (const float*)d_in[15];
    const float* wg     = (const float*)d_in[16];
    const float* wo     = (const float*)d_in[17];
    const float* pair_w = (const float*)d_in[18];
    const float* pair_b = (const float*)d_in[19];
    const float* g1w    = (const float*)d_in[20];
    const float* g1b    = (const float*)d_in[21];
    const float* g2w    = (const float*)d_in[22];
    const float* g2b    = (const float*)d_in[23];
    const float* sw1    = (const float*)d_in[24];
    const float* sw3    = (const float*)d_in[25];
    const float* sw2    = (const float*)d_in[26];
    const int*   p_idx  = (const int*)d_in[27];
    const int*   tok    = (const int*)d_in[28];
    float* out = (float*)d_out;

    size_t off = 0;
    char* base = (char*)d_ws;
    auto alloc = [&](size_t bytes) -> void* {
        void* p = base + off;
        off += (bytes + 255) & ~(size_t)255;
        return p;
    };
    ushort* hcb     = (ushort*)alloc((size_t)NT * DM * 2);
    ushort* cab     = (ushort*)alloc((size_t)NA * DA * 2);
    ushort* cwT     = (ushort*)alloc((size_t)DM * DA * 2);
    ushort* a1T     = (ushort*)alloc((size_t)256 * 128 * 2);
    ushort* a2T     = (ushort*)alloc((size_t)256 * 128 * 2);
    ushort* wqT     = (ushort*)alloc((size_t)128 * 128 * 2);
    ushort* wkT     = (ushort*)alloc((size_t)128 * 128 * 2);
    ushort* wvT     = (ushort*)alloc((size_t)128 * 128 * 2);
    ushort* wgT     = (ushort*)alloc((size_t)128 * 128 * 2);
    ushort* woT     = (ushort*)alloc((size_t)128 * 128 * 2);
    ushort* g1T     = (ushort*)alloc((size_t)128 * 128 * 2);
    ushort* g2T     = (ushort*)alloc((size_t)128 * 128 * 2);
    ushort* s1T     = (ushort*)alloc((size_t)512 * 128 * 2);
    ushort* s3T     = (ushort*)alloc((size_t)512 * 128 * 2);
    ushort* s2T     = (ushort*)alloc((size_t)128 * 512 * 2);
    ushort* cond_bf = (ushort*)alloc((size_t)NA * DA * 2);
    float*  gb1     = (float*)alloc((size_t)NA * 256 * 4);
    float*  gb2     = (float*)alloc((size_t)NA * 256 * 4);
    float*  gate1   = (float*)alloc((size_t)NA * DA * 4);
    float*  gate2   = (float*)alloc((size_t)NA * DA * 4);
    float*  Qb      = (float*)alloc((size_t)NA * DA * 4);
    float*  Kb      = (float*)alloc((size_t)NA * DA * 4);
    float*  Vb      = (float*)alloc((size_t)NA * DA * 4);
    float*  sG      = (float*)alloc((size_t)NA * DA * 4);
    float*  band    = (float*)alloc((size_t)NA * HH * BAND * 4);
    float*  q1      = (float*)alloc((size_t)NA * DA * 4);

    k_prep<<<dim3(64, 17), 256, 0, stream>>>(
        h_cond, c_atom, cond_w, ad1w, ad2w, wq, wk, wv, wg, wo,
        g1w, g2w, sw1, sw3, sw2,
        hcb, cab, cwT, a1T, a2T, wqT, wkT, wvT, wgT, woT,
        g1T, g2T, s1T, s3T, s2T, band, out);
    k_cond<<<dim3(64, 6), 256, 0, stream>>>(hcb, tok, cwT, t_emb, cond_b, cond_bf,
                                            p_lm, pair_w, pair_b, p_idx, band);
    k_modgate<<<dim3(64, 12), 256, 0, stream>>>(cond_bf, cab, a1T, a2T, g1T, g2T,
                                                ad1b, ad2b, g1b, g2b,
                                                gb1, gb2, gate1, gate2);
    k_qkvg<<<dim3(64, 2, 4), 256, 0, stream>>>(q, gb1, ln_g, ln_b,
                                               wqT, wkT, wvT, wgT, Qb, Kb, Vb, sG);
    k_attnwo<<<NA / 16, 512, 0, stream>>>(Qb, Kb, Vb, band, q, sG, gate1, woT, q1);
    k_ffn<<<dim3(NA / 16, 4), 256, 0, stream>>>(q1, gb2, gate2, s1T, s3T, s2T, out);
    (void)in_sizes; (void)n_in; (void)out_size; (void)ws_size;
}

// Round 6
// 186.724 us; speedup vs baseline: 1.9764x; 1.0645x over previous
//
#include <hip/hip_runtime.h>
#include <math.h>

#define NA   4096
#define DA   128
#define DM   512
#define NT   1024
#define HH   4
#define DF   512
#define PP   32768
#define WIN  16
#define BAND 33

typedef __attribute__((ext_vector_type(8))) short bf16x8;
typedef __attribute__((ext_vector_type(4))) float f32x4;

__device__ __forceinline__ float sigmoidf_(float x) { return 1.0f / (1.0f + __expf(-x)); }
__device__ __forceinline__ ushort f2bf(float f) {
    union { float f; unsigned int i; } x; x.f = f;
    unsigned int r = x.i + 0x7fffu + ((x.i >> 16) & 1u);
    return (ushort)(r >> 16);
}
__device__ __forceinline__ float bf2f(ushort u) {
    union { unsigned int i; float f; } x; x.i = ((unsigned int)u) << 16;
    return x.f;
}

// ---------------------------------------------------------------------------
// Prep: bf16 weight transposes (32x32 LDS tiles), activation converts,
// zero band.  grid (64, 16)
// ---------------------------------------------------------------------------
__global__ __launch_bounds__(256) void k_prep(
    const float* __restrict__ hc, const float* __restrict__ ca,
    const float* __restrict__ cw, const float* __restrict__ a1, const float* __restrict__ a2,
    const float* __restrict__ wq, const float* __restrict__ wk, const float* __restrict__ wv,
    const float* __restrict__ wg, const float* __restrict__ wo,
    const float* __restrict__ g1, const float* __restrict__ g2,
    const float* __restrict__ s1, const float* __restrict__ s3, const float* __restrict__ s2,
    ushort* hcb, ushort* cab, ushort* cwT, ushort* a1T, ushort* a2T,
    ushort* wqT, ushort* wkT, ushort* wvT, ushort* wgT, ushort* woT,
    ushort* g1T, ushort* g2T, ushort* s1T, ushort* s3T, ushort* s2T,
    float* band)
{
    __shared__ float tile[32][33];
    const int y = blockIdx.y, bx = blockIdx.x, tid = threadIdx.x;
    if (y <= 1) {
        const float4* src = (const float4*)(y == 0 ? hc : ca);
        ushort* dst = y == 0 ? hcb : cab;
        for (int i = bx * 256 + tid; i < 131072; i += 16384) {
            float4 v = src[i];
            ushort4 st; st.x = f2bf(v.x); st.y = f2bf(v.y); st.z = f2bf(v.z); st.w = f2bf(v.w);
            *(ushort4*)&dst[(size_t)i * 4] = st;
        }
        return;
    }
    if (y == 15) {
        float4 z = {0.f, 0.f, 0.f, 0.f};
        float4* b4 = (float4*)band;
        for (int i = bx * 256 + tid; i < 135168; i += 16384) b4[i] = z;
        return;
    }
    const float* src; ushort* dst; int K, N;
    switch (y) {
        case 2:  src = cw; dst = cwT; K = 512; N = 128; break;
        case 3:  src = a1; dst = a1T; K = 128; N = 256; break;
        case 4:  src = a2; dst = a2T; K = 128; N = 256; break;
        case 5:  src = wq; dst = wqT; K = 128; N = 128; break;
        case 6:  src = wk; dst = wkT; K = 128; N = 128; break;
        case 7:  src = wv; dst = wvT; K = 128; N = 128; break;
        case 8:  src = wg; dst = wgT; K = 128; N = 128; break;
        case 9:  src = wo; dst = woT; K = 128; N = 128; break;
        case 10: src = g1; dst = g1T; K = 128; N = 128; break;
        case 11: src = g2; dst = g2T; K = 128; N = 128; break;
        case 12: src = s1; dst = s1T; K = 128; N = 512; break;
        case 13: src = s3; dst = s3T; K = 128; N = 512; break;
        default: src = s2; dst = s2T; K = 512; N = 128; break;
    }
    const int tn_cnt = N >> 5;
    if (bx >= (K >> 5) * tn_cnt) return;
    const int k0 = (bx / tn_cnt) << 5, n0 = (bx % tn_cnt) << 5;
    {
        int r = tid >> 3, c = (tid & 7) << 2;
        float4 v = *(const float4*)&src[(size_t)(k0 + r) * N + n0 + c];
        tile[r][c + 0] = v.x; tile[r][c + 1] = v.y;
        tile[r][c + 2] = v.z; tile[r][c + 3] = v.w;
    }
    __syncthreads();
    {
        int rn = tid >> 3, ck = (tid & 7) << 2;
        ushort4 st;
        st.x = f2bf(tile[ck + 0][rn]);
        st.y = f2bf(tile[ck + 1][rn]);
        st.z = f2bf(tile[ck + 2][rn]);
        st.w = f2bf(tile[ck + 3][rn]);
        *(ushort4*)&dst[(size_t)(n0 + rn) * K + k0 + ck] = st;
    }
}

// ---------------------------------------------------------------------------
// MFMA helper for single-WT streams
// ---------------------------------------------------------------------------
template<int K, int NF>
__device__ __forceinline__ void gemm_core(
    const ushort* __restrict__ Arow, const ushort* __restrict__ WTcol,
    f32x4* acc, int ko)
{
    #pragma unroll
    for (int ks = 0; ks < K / 32; ++ks) {
        bf16x8 a = *(const bf16x8*)(Arow + ks * 32 + ko);
        #pragma unroll
        for (int nf = 0; nf < NF; ++nf) {
            bf16x8 b = *(const bf16x8*)(WTcol + (size_t)nf * 16 * K + ks * 32 + ko);
            acc[nf] = __builtin_amdgcn_mfma_f32_16x16x32_bf16(a, b, acc[nf], 0, 0, 0);
        }
    }
}

// ---------------------------------------------------------------------------
// cond GEMM (y<4) + pair-bias scatter (y=4,5).  grid (64, 6)
// ---------------------------------------------------------------------------
__global__ __launch_bounds__(256) void k_cond(
    const ushort* __restrict__ hcb, const int* __restrict__ tok,
    const ushort* __restrict__ cwT, const float* __restrict__ t_emb,
    const float* __restrict__ cond_b, ushort* __restrict__ cond_bf,
    const float* __restrict__ p_lm, const float* __restrict__ pair_w,
    const float* __restrict__ pair_b, const int* __restrict__ p_idx,
    float* __restrict__ band)
{
    const int tid = threadIdx.x, y = blockIdx.y;
    if (y >= 4) {
        int p = ((y - 4) * 64 + blockIdx.x) * 256 + tid;   // covers PP exactly
        int i = p_idx[2 * p], j = p_idx[2 * p + 1];
        int d = j - i + WIN;
        if (d < 0 || d > 2 * WIN) return;
        float v0 = pair_b[0], v1 = pair_b[1], v2 = pair_b[2], v3 = pair_b[3];
        #pragma unroll
        for (int k = 0; k < 16; ++k) {
            float a = p_lm[p * 16 + k];
            v0 = fmaf(a, pair_w[k * 4 + 0], v0);
            v1 = fmaf(a, pair_w[k * 4 + 1], v1);
            v2 = fmaf(a, pair_w[k * 4 + 2], v2);
            v3 = fmaf(a, pair_w[k * 4 + 3], v3);
        }
        size_t base = ((size_t)i * HH) * BAND + d;
        band[base + 0 * BAND] = v0;
        band[base + 1 * BAND] = v1;
        band[base + 2 * BAND] = v2;
        band[base + 3 * BAND] = v3;
        return;
    }
    const int l = tid & 63, w = tid >> 6, cl = l & 15, ko = (l >> 4) * 8;
    const int m0 = blockIdx.x * 64, n0 = y * 32;
    const int trow = tok[m0 + w * 16 + cl];
    f32x4 acc[2] = {};
    gemm_core<512, 2>(hcb + (size_t)trow * DM, cwT + (size_t)(n0 + cl) * DM, acc, ko);
    const int r0 = m0 + w * 16 + (l >> 4) * 4;
    #pragma unroll
    for (int nf = 0; nf < 2; ++nf) {
        int col = n0 + nf * 16 + cl;
        float add = t_emb[col] + cond_b[col];
        #pragma unroll
        for (int r = 0; r < 4; ++r)
            cond_bf[(size_t)(r0 + r) * DA + col] = f2bf(acc[nf][r] + add);
    }
}

// ---------------------------------------------------------------------------
// Paired modulators: y<4 -> {gb1,gb2} cols y*64; y=4,5 -> {gate1,gate2}.
// A read once per block, two WT streams.  grid (64, 6). All outputs bf16.
// ---------------------------------------------------------------------------
__global__ __launch_bounds__(256) void k_modgate(
    const ushort* __restrict__ cond_bf, const ushort* __restrict__ cab,
    const ushort* __restrict__ a1T, const ushort* __restrict__ a2T,
    const ushort* __restrict__ g1T, const ushort* __restrict__ g2T,
    const float* __restrict__ ad1b, const float* __restrict__ ad2b,
    const float* __restrict__ g1b, const float* __restrict__ g2b,
    ushort* __restrict__ gb1, ushort* __restrict__ gb2,
    ushort* __restrict__ gate1, ushort* __restrict__ gate2)
{
    const int tid = threadIdx.x, y = blockIdx.y;
    const int l = tid & 63, w = tid >> 6, cl = l & 15, ko = (l >> 4) * 8;
    const int m0 = blockIdx.x * 64;
    const int gatep = (y >= 4);
    const int n0 = gatep ? (y - 4) * 64 : y * 64;
    const ushort* A  = gatep ? cab : cond_bf;
    const ushort* W1 = gatep ? g1T : a1T;
    const ushort* W2 = gatep ? g2T : a2T;
    const float* b1 = gatep ? g1b : ad1b;
    const float* b2 = gatep ? g2b : ad2b;
    ushort* O1 = gatep ? gate1 : gb1;
    ushort* O2 = gatep ? gate2 : gb2;
    const int ldo = gatep ? DA : 256;

    const ushort* Arow = A + (size_t)(m0 + w * 16 + cl) * DA;
    const ushort* W1c = W1 + (size_t)(n0 + cl) * DA;
    const ushort* W2c = W2 + (size_t)(n0 + cl) * DA;
    f32x4 acc1[4] = {}, acc2[4] = {};
    #pragma unroll
    for (int ks = 0; ks < 4; ++ks) {
        bf16x8 a = *(const bf16x8*)(Arow + ks * 32 + ko);
        #pragma unroll
        for (int nf = 0; nf < 4; ++nf) {
            bf16x8 w1v = *(const bf16x8*)(W1c + (size_t)nf * 16 * DA + ks * 32 + ko);
            acc1[nf] = __builtin_amdgcn_mfma_f32_16x16x32_bf16(a, w1v, acc1[nf], 0, 0, 0);
            bf16x8 w2v = *(const bf16x8*)(W2c + (size_t)nf * 16 * DA + ks * 32 + ko);
            acc2[nf] = __builtin_amdgcn_mfma_f32_16x16x32_bf16(a, w2v, acc2[nf], 0, 0, 0);
        }
    }
    const int r0 = m0 + w * 16 + (l >> 4) * 4;
    #pragma unroll
    for (int nf = 0; nf < 4; ++nf) {
        int col = n0 + nf * 16 + cl;
        float bb1 = b1[col], bb2 = b2[col];
        #pragma unroll
        for (int r = 0; r < 4; ++r) {
            float v1 = acc1[nf][r] + bb1;
            float v2 = acc2[nf][r] + bb2;
            if (gatep) { v1 = sigmoidf_(v1); v2 = sigmoidf_(v2); }
            O1[(size_t)(r0 + r) * ldo + col] = f2bf(v1);
            O2[(size_t)(r0 + r) * ldo + col] = f2bf(v2);
        }
    }
}

// ---------------------------------------------------------------------------
// LN1 + adaLN modulate -> qn_bf (once). Block = 4 rows. grid 1024.
// ---------------------------------------------------------------------------
__global__ __launch_bounds__(256) void k_ln1(
    const float* __restrict__ q, const ushort* __restrict__ gb1,
    const float* __restrict__ ln_g, const float* __restrict__ ln_b,
    ushort* __restrict__ qn_bf)
{
    const int w = threadIdx.x >> 6, l = threadIdx.x & 63;
    const int row = blockIdx.x * 4 + w;
    float2 xv = *(const float2*)&q[(size_t)row * DA + 2 * l];
    float sum = xv.x + xv.y, sq = xv.x * xv.x + xv.y * xv.y;
    #pragma unroll
    for (int off = 1; off <= 32; off <<= 1) {
        sum += __shfl_xor(sum, off);
        sq  += __shfl_xor(sq,  off);
    }
    float m = sum * (1.0f / DA);
    float rs = rsqrtf(sq * (1.0f / DA) - m * m + 1e-5f);
    ushort2 gu = *(const ushort2*)&gb1[(size_t)row * 256 + 2 * l];
    ushort2 bu = *(const ushort2*)&gb1[(size_t)row * 256 + 128 + 2 * l];
    float2 lg = *(const float2*)&ln_g[2 * l];
    float2 lb = *(const float2*)&ln_b[2 * l];
    float xn0 = (xv.x - m) * rs * lg.x + lb.x;
    float xn1 = (xv.y - m) * rs * lg.y + lb.y;
    ushort2 st;
    st.x = f2bf((1.f + bf2f(gu.x)) * xn0 + bf2f(bu.x));
    st.y = f2bf((1.f + bf2f(gu.y)) * xn1 + bf2f(bu.y));
    *(ushort2*)&qn_bf[(size_t)row * DA + 2 * l] = st;
}

// ---------------------------------------------------------------------------
// Q,K,V (f32) and sigmoid(G) (bf16) from qn_bf.  grid (64, 2, 4).
// ---------------------------------------------------------------------------
__global__ __launch_bounds__(256) void k_qkvg(
    const ushort* __restrict__ qn_bf,
    const ushort* __restrict__ wqT, const ushort* __restrict__ wkT,
    const ushort* __restrict__ wvT, const ushort* __restrict__ wgT,
    float* __restrict__ Qb, float* __restrict__ Kb,
    float* __restrict__ Vb, ushort* __restrict__ sG)
{
    const int tid = threadIdx.x, l = tid & 63, w = tid >> 6;
    const int cl = l & 15, kq = l >> 4, ko = kq * 8;
    const int m0 = blockIdx.x * 64, n0 = blockIdx.y * 64, z = blockIdx.z;
    const ushort* WT = (z == 0) ? wqT : (z == 1) ? wkT : (z == 2) ? wvT : wgT;
    f32x4 acc[4] = {};
    gemm_core<128, 4>(qn_bf + (size_t)(m0 + w * 16 + cl) * DA,
                      WT + (size_t)(n0 + cl) * DA, acc, ko);
    const int r0 = m0 + w * 16 + kq * 4;
    float* O = (z == 0) ? Qb : (z == 1) ? Kb : Vb;
    #pragma unroll
    for (int nf = 0; nf < 4; ++nf) {
        int col = n0 + nf * 16 + cl;
        #pragma unroll
        for (int r = 0; r < 4; ++r) {
            size_t rc = (size_t)(r0 + r) * DA + col;
            if (z == 3) sG[rc] = f2bf(sigmoidf_(acc[nf][r]));
            else O[rc] = acc[nf][r];
        }
    }
}

// ---------------------------------------------------------------------------
// Fused banded attention (f32) + wo MFMA + gated residual.  grid 256, 512 thr.
// ---------------------------------------------------------------------------
__global__ __launch_bounds__(512) void k_attnwo(
    const float* __restrict__ Qb, const float* __restrict__ Kb,
    const float* __restrict__ Vb, const float* __restrict__ band,
    const float* __restrict__ q, const ushort* __restrict__ sG,
    const ushort* __restrict__ gate1, const ushort* __restrict__ woT,
    float* __restrict__ q1)
{
    __shared__ ushort att_s[16 * 128];
    const int tid = threadIdx.x;
    const int r0 = blockIdx.x * 16;
    {
        const int g = tid >> 3, l3 = tid & 7;
        const int rl = g >> 2, h = g & 3;
        const int i = r0 + rl;
        const float scale = 0.17677669529663687f;   // 1/sqrt(32)
        float4 qr = *(const float4*)(Qb + (size_t)i * DA + h * 32 + l3 * 4);
        const float* brow = band + ((size_t)i * HH + h) * BAND;
        float s[BAND];
        float m = -1e30f;
        #pragma unroll
        for (int jo = 0; jo < BAND; ++jo) {
            int j = i - WIN + jo;
            float sv = -1e30f;
            if ((unsigned)j < NA) {
                float4 kk = *(const float4*)(Kb + (size_t)j * DA + h * 32 + l3 * 4);
                float d = 0.f;
                d = fmaf(qr.x, kk.x, d); d = fmaf(qr.y, kk.y, d);
                d = fmaf(qr.z, kk.z, d); d = fmaf(qr.w, kk.w, d);
                d += __shfl_xor(d, 1);
                d += __shfl_xor(d, 2);
                d += __shfl_xor(d, 4);
                sv = fmaf(d, scale, brow[jo]);
            }
            s[jo] = sv;
            m = fmaxf(m, sv);
        }
        float lsum = 0.f;
        #pragma unroll
        for (int jo = 0; jo < BAND; ++jo) {
            float p = __expf(s[jo] - m);
            s[jo] = p;
            lsum += p;
        }
        float inv = 1.0f / lsum;
        float4 o = {0.f, 0.f, 0.f, 0.f};
        #pragma unroll
        for (int jo = 0; jo < BAND; ++jo) {
            int j = i - WIN + jo;
            if ((unsigned)j < NA) {
                float4 v = *(const float4*)(Vb + (size_t)j * DA + h * 32 + l3 * 4);
                o.x = fmaf(s[jo], v.x, o.x);
                o.y = fmaf(s[jo], v.y, o.y);
                o.z = fmaf(s[jo], v.z, o.z);
                o.w = fmaf(s[jo], v.w, o.w);
            }
        }
        ushort4 st;
        st.x = f2bf(o.x * inv); st.y = f2bf(o.y * inv);
        st.z = f2bf(o.z * inv); st.w = f2bf(o.w * inv);
        int byte = rl * 256 + h * 64 + l3 * 8;
        byte ^= (rl & 7) << 4;
        *(ushort4*)((char*)att_s + byte) = st;
    }
    __syncthreads();
    {
        const int l = tid & 63, w = tid >> 6;      // 8 waves, 16 cols each
        const int cl = l & 15, kq = l >> 4, ko = kq * 8;
        const int n0 = w * 16;
        f32x4 acc = {0.f, 0.f, 0.f, 0.f};
        #pragma unroll
        for (int ks = 0; ks < 4; ++ks) {
            int byteA = cl * 256 + (ks * 32 + ko) * 2;
            byteA ^= (cl & 7) << 4;
            bf16x8 a = *(const bf16x8*)((char*)att_s + byteA);
            bf16x8 b = *(const bf16x8*)(woT + (size_t)(n0 + cl) * DA + ks * 32 + ko);
            acc = __builtin_amdgcn_mfma_f32_16x16x32_bf16(a, b, acc, 0, 0, 0);
        }
        #pragma unroll
        for (int r = 0; r < 4; ++r) {
            int row = r0 + kq * 4 + r, col = n0 + cl;
            size_t rc = (size_t)row * DA + col;
            q1[rc] = (q[rc] + bf2f(sG[rc]) * acc[r]) * (1.f + bf2f(gate1[rc]));
        }
    }
}

// ---------------------------------------------------------------------------
// Fused FFN, full-K: LN2 in-reg + sw1/sw3 MFMA -> 16x512 LDS hb -> sw2 MFMA
// + gated residual.  grid 256, 512 thr (8 waves), 16 rows per block.
// ---------------------------------------------------------------------------
__global__ __launch_bounds__(512) void k_ffn(
    const float* __restrict__ q1, const ushort* __restrict__ gb2,
    const ushort* __restrict__ gate2,
    const ushort* __restrict__ s1T, const ushort* __restrict__ s3T,
    const ushort* __restrict__ s2T, float* __restrict__ out)
{
    __shared__ ushort hbs[16 * 512];
    const int tid = threadIdx.x, l = tid & 63, w = tid >> 6;
    const int cl = l & 15, kq = l >> 4, ko = kq * 8;
    const int m0 = blockIdx.x * 16;
    const int row = m0 + cl;

    // LN2 (each wave computes its own copy; data L1-hot)
    float qv[4][8];
    float sum = 0.f, sq = 0.f;
    #pragma unroll
    for (int ks = 0; ks < 4; ++ks) {
        float4 v0 = *(const float4*)&q1[(size_t)row * DA + ks * 32 + ko];
        float4 v1 = *(const float4*)&q1[(size_t)row * DA + ks * 32 + ko + 4];
        qv[ks][0] = v0.x; qv[ks][1] = v0.y; qv[ks][2] = v0.z; qv[ks][3] = v0.w;
        qv[ks][4] = v1.x; qv[ks][5] = v1.y; qv[ks][6] = v1.z; qv[ks][7] = v1.w;
        sum += v0.x + v0.y + v0.z + v0.w + v1.x + v1.y + v1.z + v1.w;
        sq += v0.x * v0.x + v0.y * v0.y + v0.z * v0.z + v0.w * v0.w
            + v1.x * v1.x + v1.y * v1.y + v1.z * v1.z + v1.w * v1.w;
    }
    sum += __shfl_xor(sum, 16); sq += __shfl_xor(sq, 16);
    sum += __shfl_xor(sum, 32); sq += __shfl_xor(sq, 32);
    float mean = sum * (1.0f / DA);
    float rs = rsqrtf(sq * (1.0f / DA) - mean * mean + 1e-5f);

    bf16x8 afr[4];
    #pragma unroll
    for (int ks = 0; ks < 4; ++ks) {
        int k = ks * 32 + ko;
        ushort4 g0 = *(const ushort4*)&gb2[(size_t)row * 256 + k];
        ushort4 g1v = *(const ushort4*)&gb2[(size_t)row * 256 + k + 4];
        ushort4 b0 = *(const ushort4*)&gb2[(size_t)row * 256 + 128 + k];
        ushort4 b1v = *(const ushort4*)&gb2[(size_t)row * 256 + 128 + k + 4];
        float gg[8] = {bf2f(g0.x), bf2f(g0.y), bf2f(g0.z), bf2f(g0.w),
                       bf2f(g1v.x), bf2f(g1v.y), bf2f(g1v.z), bf2f(g1v.w)};
        float bb[8] = {bf2f(b0.x), bf2f(b0.y), bf2f(b0.z), bf2f(b0.w),
                       bf2f(b1v.x), bf2f(b1v.y), bf2f(b1v.z), bf2f(b1v.w)};
        #pragma unroll
        for (int j = 0; j < 8; ++j) {
            float xn = (qv[ks][j] - mean) * rs;
            afr[ks][j] = (short)f2bf((1.f + gg[j]) * xn + bb[j]);
        }
    }

    // sw1/sw3: wave w -> hb cols w*64 .. w*64+63
    {
        const int c0 = w * 64;
        const ushort* W1 = s1T + (size_t)(c0 + cl) * DA;
        const ushort* W3 = s3T + (size_t)(c0 + cl) * DA;
        f32x4 acc1[4] = {}, acc3[4] = {};
        #pragma unroll
        for (int ks = 0; ks < 4; ++ks) {
            #pragma unroll
            for (int nf = 0; nf < 4; ++nf) {
                bf16x8 b1 = *(const bf16x8*)(W1 + (size_t)nf * 16 * DA + ks * 32 + ko);
                acc1[nf] = __builtin_amdgcn_mfma_f32_16x16x32_bf16(afr[ks], b1, acc1[nf], 0, 0, 0);
                bf16x8 b3 = *(const bf16x8*)(W3 + (size_t)nf * 16 * DA + ks * 32 + ko);
                acc3[nf] = __builtin_amdgcn_mfma_f32_16x16x32_bf16(afr[ks], b3, acc3[nf], 0, 0, 0);
            }
        }
        #pragma unroll
        for (int nf = 0; nf < 4; ++nf) {
            #pragma unroll
            for (int r = 0; r < 4; ++r) {
                float x1 = acc1[nf][r], x3 = acc3[nf][r];
                float h = x1 * sigmoidf_(x1) * x3;
                int rr = kq * 4 + r;
                int col = c0 + nf * 16 + cl;
                int byte = rr * 1024 + col * 2;
                byte ^= (rr & 7) << 4;
                *(ushort*)((char*)hbs + byte) = f2bf(h);
            }
        }
    }
    __syncthreads();
    // sw2: wave w -> out cols w*16 .. w*16+15, K = 512
    {
        const int n0 = w * 16;
        const ushort* W2 = s2T + (size_t)(n0 + cl) * DF;
        f32x4 acc = {0.f, 0.f, 0.f, 0.f};
        #pragma unroll
        for (int ks = 0; ks < 16; ++ks) {
            int byteA = cl * 1024 + (ks * 32 + ko) * 2;
            byteA ^= (cl & 7) << 4;
            bf16x8 a = *(const bf16x8*)((char*)hbs + byteA);
            bf16x8 b = *(const bf16x8*)(W2 + ks * 32 + ko);
            acc = __builtin_amdgcn_mfma_f32_16x16x32_bf16(a, b, acc, 0, 0, 0);
        }
        #pragma unroll
        for (int r = 0; r < 4; ++r) {
            int rowg = m0 + kq * 4 + r, col = n0 + cl;
            size_t rc = (size_t)rowg * DA + col;
            out[rc] = q1[rc] + bf2f(gate2[rc]) * acc[r];
        }
    }
}

// ---------------------------------------------------------------------------
extern "C" void kernel_launch(void* const* d_in, const int* in_sizes, int n_in,
                              void* d_out, int out_size, void* d_ws, size_t ws_size,
                              hipStream_t stream)
{
    const float* q      = (const float*)d_in[0];
    const float* c_atom = (const float*)d_in[1];
    const float* h_cond = (const float*)d_in[2];
    const float* p_lm   = (const float*)d_in[3];
    const float* t_emb  = (const float*)d_in[4];
    const float* cond_w = (const float*)d_in[5];
    const float* cond_b = (const float*)d_in[6];
    const float* ad1w   = (const float*)d_in[7];
    const float* ad1b   = (const float*)d_in[8];
    const float* ad2w   = (const float*)d_in[9];
    const float* ad2b   = (const float*)d_in[10];
    const float* ln_g   = (const float*)d_in[11];
    const float* ln_b   = (const float*)d_in[12];
    const float* wq     = (const float*)d_in[13];
    const float* wk     = (const float*)d_in[14];
    const float* wv     = (const float*)d_in[15];
    const float* wg     = (const float*)d_in[16];
    const float* wo     = (const float*)d_in[17];
    const float* pair_w = (const float*)d_in[18];
    const float* pair_b = (const float*)d_in[19];
    const float* g1w    = (const float*)d_in[20];
    const float* g1b    = (const float*)d_in[21];
    const float* g2w    = (const float*)d_in[22];
    const float* g2b    = (const float*)d_in[23];
    const float* sw1    = (const float*)d_in[24];
    const float* sw3    = (const float*)d_in[25];
    const float* sw2    = (const float*)d_in[26];
    const int*   p_idx  = (const int*)d_in[27];
    const int*   tok    = (const int*)d_in[28];
    float* out = (float*)d_out;

    size_t off = 0;
    char* base = (char*)d_ws;
    auto alloc = [&](size_t bytes) -> void* {
        void* p = base + off;
        off += (bytes + 255) & ~(size_t)255;
        return p;
    };
    ushort* hcb     = (ushort*)alloc((size_t)NT * DM * 2);
    ushort* cab     = (ushort*)alloc((size_t)NA * DA * 2);
    ushort* cwT     = (ushort*)alloc((size_t)DM * DA * 2);
    ushort* a1T     = (ushort*)alloc((size_t)256 * 128 * 2);
    ushort* a2T     = (ushort*)alloc((size_t)256 * 128 * 2);
    ushort* wqT     = (ushort*)alloc((size_t)128 * 128 * 2);
    ushort* wkT     = (ushort*)alloc((size_t)128 * 128 * 2);
    ushort* wvT     = (ushort*)alloc((size_t)128 * 128 * 2);
    ushort* wgT     = (ushort*)alloc((size_t)128 * 128 * 2);
    ushort* woT     = (ushort*)alloc((size_t)128 * 128 * 2);
    ushort* g1T     = (ushort*)alloc((size_t)128 * 128 * 2);
    ushort* g2T     = (ushort*)alloc((size_t)128 * 128 * 2);
    ushort* s1T     = (ushort*)alloc((size_t)512 * 128 * 2);
    ushort* s3T     = (ushort*)alloc((size_t)512 * 128 * 2);
    ushort* s2T     = (ushort*)alloc((size_t)128 * 512 * 2);
    ushort* cond_bf = (ushort*)alloc((size_t)NA * DA * 2);
    ushort* gb1     = (ushort*)alloc((size_t)NA * 256 * 2);
    ushort* gb2     = (ushort*)alloc((size_t)NA * 256 * 2);
    ushort* gate1   = (ushort*)alloc((size_t)NA * DA * 2);
    ushort* gate2   = (ushort*)alloc((size_t)NA * DA * 2);
    ushort* qn_bf   = (ushort*)alloc((size_t)NA * DA * 2);
    float*  Qb      = (float*)alloc((size_t)NA * DA * 4);
    float*  Kb      = (float*)alloc((size_t)NA * DA * 4);
    float*  Vb      = (float*)alloc((size_t)NA * DA * 4);
    ushort* sG      = (ushort*)alloc((size_t)NA * DA * 2);
    float*  band    = (float*)alloc((size_t)NA * HH * BAND * 4);
    float*  q1      = (float*)alloc((size_t)NA * DA * 4);

    k_prep<<<dim3(64, 16), 256, 0, stream>>>(
        h_cond, c_atom, cond_w, ad1w, ad2w, wq, wk, wv, wg, wo,
        g1w, g2w, sw1, sw3, sw2,
        hcb, cab, cwT, a1T, a2T, wqT, wkT, wvT, wgT, woT,
        g1T, g2T, s1T, s3T, s2T, band);
    k_cond<<<dim3(64, 6), 256, 0, stream>>>(hcb, tok, cwT, t_emb, cond_b, cond_bf,
                                            p_lm, pair_w, pair_b, p_idx, band);
    k_modgate<<<dim3(64, 6), 256, 0, stream>>>(cond_bf, cab, a1T, a2T, g1T, g2T,
                                               ad1b, ad2b, g1b, g2b,
                                               gb1, gb2, gate1, gate2);
    k_ln1<<<NA / 4, 256, 0, stream>>>(q, gb1, ln_g, ln_b, qn_bf);
    k_qkvg<<<dim3(64, 2, 4), 256, 0, stream>>>(qn_bf, wqT, wkT, wvT, wgT, Qb, Kb, Vb, sG);
    k_attnwo<<<NA / 16, 512, 0, stream>>>(Qb, Kb, Vb, band, q, sG, gate1, woT, q1);
    k_ffn<<<NA / 16, 512, 0, stream>>>(q1, gb2, gate2, s1T, s3T, s2T, out);
    (void)in_sizes; (void)n_in; (void)out_size; (void)ws_size;
}

// Round 7
// 168.522 us; speedup vs baseline: 2.1899x; 1.1080x over previous
//
#include <hip/hip_runtime.h>
#include <math.h>

#define NA   4096
#define DA   128
#define DM   512
#define NT   1024
#define HH   4
#define DF   512
#define PP   32768
#define WIN  16
#define BAND 33
#define KSTR 132   // padded f32 LDS row stride (breaks bank alignment)

typedef __attribute__((ext_vector_type(8))) short bf16x8;
typedef __attribute__((ext_vector_type(4))) float f32x4;

__device__ __forceinline__ float sigmoidf_(float x) { return 1.0f / (1.0f + __expf(-x)); }
__device__ __forceinline__ ushort f2bf(float f) {
    union { float f; unsigned int i; } x; x.f = f;
    unsigned int r = x.i + 0x7fffu + ((x.i >> 16) & 1u);
    return (ushort)(r >> 16);
}

// ---------------------------------------------------------------------------
// Prep: bf16 weight transposes (32x32 LDS tiles), activation converts,
// zero band.  grid (64, 16)
// ---------------------------------------------------------------------------
__global__ __launch_bounds__(256) void k_prep(
    const float* __restrict__ hc, const float* __restrict__ ca,
    const float* __restrict__ cw, const float* __restrict__ a1, const float* __restrict__ a2,
    const float* __restrict__ wq, const float* __restrict__ wk, const float* __restrict__ wv,
    const float* __restrict__ wg, const float* __restrict__ wo,
    const float* __restrict__ g1, const float* __restrict__ g2,
    const float* __restrict__ s1, const float* __restrict__ s3, const float* __restrict__ s2,
    ushort* hcb, ushort* cab, ushort* cwT, ushort* a1T, ushort* a2T,
    ushort* wqT, ushort* wkT, ushort* wvT, ushort* wgT, ushort* woT,
    ushort* g1T, ushort* g2T, ushort* s1T, ushort* s3T, ushort* s2T,
    float* band)
{
    __shared__ float tile[32][33];
    const int y = blockIdx.y, bx = blockIdx.x, tid = threadIdx.x;
    if (y <= 1) {
        const float4* src = (const float4*)(y == 0 ? hc : ca);
        ushort* dst = y == 0 ? hcb : cab;
        for (int i = bx * 256 + tid; i < 131072; i += 16384) {
            float4 v = src[i];
            ushort4 st; st.x = f2bf(v.x); st.y = f2bf(v.y); st.z = f2bf(v.z); st.w = f2bf(v.w);
            *(ushort4*)&dst[(size_t)i * 4] = st;
        }
        return;
    }
    if (y == 15) {
        float4 z = {0.f, 0.f, 0.f, 0.f};
        float4* b4 = (float4*)band;
        for (int i = bx * 256 + tid; i < 135168; i += 16384) b4[i] = z;
        return;
    }
    const float* src; ushort* dst; int K, N;
    switch (y) {
        case 2:  src = cw; dst = cwT; K = 512; N = 128; break;
        case 3:  src = a1; dst = a1T; K = 128; N = 256; break;
        case 4:  src = a2; dst = a2T; K = 128; N = 256; break;
        case 5:  src = wq; dst = wqT; K = 128; N = 128; break;
        case 6:  src = wk; dst = wkT; K = 128; N = 128; break;
        case 7:  src = wv; dst = wvT; K = 128; N = 128; break;
        case 8:  src = wg; dst = wgT; K = 128; N = 128; break;
        case 9:  src = wo; dst = woT; K = 128; N = 128; break;
        case 10: src = g1; dst = g1T; K = 128; N = 128; break;
        case 11: src = g2; dst = g2T; K = 128; N = 128; break;
        case 12: src = s1; dst = s1T; K = 128; N = 512; break;
        case 13: src = s3; dst = s3T; K = 128; N = 512; break;
        default: src = s2; dst = s2T; K = 512; N = 128; break;
    }
    const int tn_cnt = N >> 5;
    if (bx >= (K >> 5) * tn_cnt) return;
    const int k0 = (bx / tn_cnt) << 5, n0 = (bx % tn_cnt) << 5;
    {
        int r = tid >> 3, c = (tid & 7) << 2;
        float4 v = *(const float4*)&src[(size_t)(k0 + r) * N + n0 + c];
        tile[r][c + 0] = v.x; tile[r][c + 1] = v.y;
        tile[r][c + 2] = v.z; tile[r][c + 3] = v.w;
    }
    __syncthreads();
    {
        int rn = tid >> 3, ck = (tid & 7) << 2;
        ushort4 st;
        st.x = f2bf(tile[ck + 0][rn]);
        st.y = f2bf(tile[ck + 1][rn]);
        st.z = f2bf(tile[ck + 2][rn]);
        st.w = f2bf(tile[ck + 3][rn]);
        *(ushort4*)&dst[(size_t)(n0 + rn) * K + k0 + ck] = st;
    }
}

// ---------------------------------------------------------------------------
// condmod: blocks <256: cond GEMM (16 rows) -> LDS -> gb1/gb2 + gates (f32).
// blocks >=256: pair-bias scatter.  grid 384, 256 thr.
// ---------------------------------------------------------------------------
__global__ __launch_bounds__(256) void k_condmod(
    const ushort* __restrict__ hcb, const int* __restrict__ tok,
    const ushort* __restrict__ cwT, const float* __restrict__ t_emb,
    const float* __restrict__ cond_b, const ushort* __restrict__ cab,
    const ushort* __restrict__ a1T, const ushort* __restrict__ a2T,
    const ushort* __restrict__ g1T, const ushort* __restrict__ g2T,
    const float* __restrict__ ad1b, const float* __restrict__ ad2b,
    const float* __restrict__ g1b, const float* __restrict__ g2b,
    const float* __restrict__ p_lm, const float* __restrict__ pair_w,
    const float* __restrict__ pair_b, const int* __restrict__ p_idx,
    float* __restrict__ band,
    float* __restrict__ gb1, float* __restrict__ gb2,
    float* __restrict__ gate1, float* __restrict__ gate2)
{
    const int tid = threadIdx.x, b = blockIdx.x;
    if (b >= 256) {
        int p = (b - 256) * 256 + tid;      // 128 blocks x 256 = PP
        int i = p_idx[2 * p], j = p_idx[2 * p + 1];
        int d = j - i + WIN;
        if (d < 0 || d > 2 * WIN) return;
        float v0 = pair_b[0], v1 = pair_b[1], v2 = pair_b[2], v3 = pair_b[3];
        #pragma unroll
        for (int k = 0; k < 16; ++k) {
            float a = p_lm[p * 16 + k];
            v0 = fmaf(a, pair_w[k * 4 + 0], v0);
            v1 = fmaf(a, pair_w[k * 4 + 1], v1);
            v2 = fmaf(a, pair_w[k * 4 + 2], v2);
            v3 = fmaf(a, pair_w[k * 4 + 3], v3);
        }
        size_t base = ((size_t)i * HH) * BAND + d;
        band[base + 0 * BAND] = v0;
        band[base + 1 * BAND] = v1;
        band[base + 2 * BAND] = v2;
        band[base + 3 * BAND] = v3;
        return;
    }
    __shared__ ushort cond_s[16 * 128];
    const int l = tid & 63, wv = tid >> 6;
    const int cl = l & 15, kq = l >> 4, ko = kq * 8;
    const int r0 = b * 16;
    // cond: wave wv -> cols wv*32..+31, K=512
    {
        const int n0 = wv * 32;
        const ushort* Arow = hcb + (size_t)tok[r0 + cl] * DM;
        const ushort* Wc = cwT + (size_t)(n0 + cl) * DM;
        f32x4 acc[2] = {};
        #pragma unroll
        for (int ks = 0; ks < 16; ++ks) {
            bf16x8 a = *(const bf16x8*)(Arow + ks * 32 + ko);
            #pragma unroll
            for (int nf = 0; nf < 2; ++nf) {
                bf16x8 bb = *(const bf16x8*)(Wc + (size_t)nf * 16 * DM + ks * 32 + ko);
                acc[nf] = __builtin_amdgcn_mfma_f32_16x16x32_bf16(a, bb, acc[nf], 0, 0, 0);
            }
        }
        #pragma unroll
        for (int nf = 0; nf < 2; ++nf) {
            int col = n0 + nf * 16 + cl;
            float add = t_emb[col] + cond_b[col];
            #pragma unroll
            for (int r = 0; r < 4; ++r) {
                int row = kq * 4 + r;
                int byte = row * 256 + col * 2;
                byte ^= (row & 7) << 4;
                *(ushort*)((char*)cond_s + byte) = f2bf(acc[nf][r] + add);
            }
        }
    }
    __syncthreads();
    // gb1/gb2: wave wv -> cols wv*64..+63 of 256, A = cond_s
    {
        const int n0 = wv * 64;
        const ushort* W1c = a1T + (size_t)(n0 + cl) * DA;
        const ushort* W2c = a2T + (size_t)(n0 + cl) * DA;
        f32x4 acc1[4] = {}, acc2[4] = {};
        #pragma unroll
        for (int ks = 0; ks < 4; ++ks) {
            int byteA = cl * 256 + (ks * 32 + ko) * 2;
            byteA ^= (cl & 7) << 4;
            bf16x8 a = *(const bf16x8*)((char*)cond_s + byteA);
            #pragma unroll
            for (int nf = 0; nf < 4; ++nf) {
                bf16x8 b1 = *(const bf16x8*)(W1c + (size_t)nf * 16 * DA + ks * 32 + ko);
                acc1[nf] = __builtin_amdgcn_mfma_f32_16x16x32_bf16(a, b1, acc1[nf], 0, 0, 0);
                bf16x8 b2 = *(const bf16x8*)(W2c + (size_t)nf * 16 * DA + ks * 32 + ko);
                acc2[nf] = __builtin_amdgcn_mfma_f32_16x16x32_bf16(a, b2, acc2[nf], 0, 0, 0);
            }
        }
        #pragma unroll
        for (int nf = 0; nf < 4; ++nf) {
            int col = n0 + nf * 16 + cl;
            float b1v = ad1b[col], b2v = ad2b[col];
            #pragma unroll
            for (int r = 0; r < 4; ++r) {
                size_t rc = (size_t)(r0 + kq * 4 + r) * 256 + col;
                gb1[rc] = acc1[nf][r] + b1v;
                gb2[rc] = acc2[nf][r] + b2v;
            }
        }
    }
    // gates: wave wv -> cols wv*32..+31, A = cab rows
    {
        const int n0 = wv * 32;
        const ushort* Arow = cab + (size_t)(r0 + cl) * DA;
        const ushort* W1c = g1T + (size_t)(n0 + cl) * DA;
        const ushort* W2c = g2T + (size_t)(n0 + cl) * DA;
        f32x4 acc1[2] = {}, acc2[2] = {};
        #pragma unroll
        for (int ks = 0; ks < 4; ++ks) {
            bf16x8 a = *(const bf16x8*)(Arow + ks * 32 + ko);
            #pragma unroll
            for (int nf = 0; nf < 2; ++nf) {
                bf16x8 b1 = *(const bf16x8*)(W1c + (size_t)nf * 16 * DA + ks * 32 + ko);
                acc1[nf] = __builtin_amdgcn_mfma_f32_16x16x32_bf16(a, b1, acc1[nf], 0, 0, 0);
                bf16x8 b2 = *(const bf16x8*)(W2c + (size_t)nf * 16 * DA + ks * 32 + ko);
                acc2[nf] = __builtin_amdgcn_mfma_f32_16x16x32_bf16(a, b2, acc2[nf], 0, 0, 0);
            }
        }
        #pragma unroll
        for (int nf = 0; nf < 2; ++nf) {
            int col = n0 + nf * 16 + cl;
            float b1v = g1b[col], b2v = g2b[col];
            #pragma unroll
            for (int r = 0; r < 4; ++r) {
                size_t rc = (size_t)(r0 + kq * 4 + r) * DA + col;
                gate1[rc] = sigmoidf_(acc1[nf][r] + b1v);
                gate2[rc] = sigmoidf_(acc2[nf][r] + b2v);
            }
        }
    }
}

// ---------------------------------------------------------------------------
// Mega kernel: per 16-row block, full chain LN1->QKVG->attn->wo->LN2->FFN.
// Halo: LN1+K/V recomputed for rows [r0-16, r0+32).  grid 256, 512 thr.
// ---------------------------------------------------------------------------
__global__ __launch_bounds__(512) void k_mega(
    const float* __restrict__ qg, const float* __restrict__ gb1,
    const float* __restrict__ gb2, const float* __restrict__ gate1,
    const float* __restrict__ gate2, const float* __restrict__ ln_g,
    const float* __restrict__ ln_b, const float* __restrict__ band,
    const ushort* __restrict__ wqT, const ushort* __restrict__ wkT,
    const ushort* __restrict__ wvT, const ushort* __restrict__ wgT,
    const ushort* __restrict__ woT, const ushort* __restrict__ s1T,
    const ushort* __restrict__ s3T, const ushort* __restrict__ s2T,
    float* __restrict__ out)
{
    __shared__ ushort qn_s[48 * 128];     // swizzled bf16
    __shared__ float  K_s[48 * KSTR];
    __shared__ float  V_s[48 * KSTR];
    __shared__ float  Q_s[16 * KSTR];
    __shared__ float  sG_s[16 * KSTR];
    __shared__ float  q1_s[16 * KSTR];
    __shared__ ushort att_s[16 * 128];    // swizzled bf16
    __shared__ ushort hb_s[16 * 512];     // swizzled bf16

    const int tid = threadIdx.x;
    const int l = tid & 63, wv = tid >> 6;
    const int cl = l & 15, kq = l >> 4, ko = kq * 8;
    const int r0 = blockIdx.x * 16;
    const int hb0 = r0 - 16;

    // ---- Phase A: LN1 + adaLN modulate for 48 halo rows -> qn_s ----
    #pragma unroll
    for (int rr = 0; rr < 6; ++rr) {
        int hr = wv * 6 + rr;
        int gr = hb0 + hr;
        ushort2 st = {0, 0};
        if ((unsigned)gr < NA) {
            float2 xv = *(const float2*)&qg[(size_t)gr * DA + 2 * l];
            float sum = xv.x + xv.y, sq = xv.x * xv.x + xv.y * xv.y;
            #pragma unroll
            for (int off = 1; off <= 32; off <<= 1) {
                sum += __shfl_xor(sum, off);
                sq  += __shfl_xor(sq,  off);
            }
            float m = sum * (1.0f / DA);
            float rs = rsqrtf(sq * (1.0f / DA) - m * m + 1e-5f);
            float2 g = *(const float2*)&gb1[(size_t)gr * 256 + 2 * l];
            float2 bb = *(const float2*)&gb1[(size_t)gr * 256 + 128 + 2 * l];
            float2 lg = *(const float2*)&ln_g[2 * l];
            float2 lb = *(const float2*)&ln_b[2 * l];
            float xn0 = (xv.x - m) * rs * lg.x + lb.x;
            float xn1 = (xv.y - m) * rs * lg.y + lb.y;
            st.x = f2bf((1.f + g.x) * xn0 + bb.x);
            st.y = f2bf((1.f + g.y) * xn1 + bb.y);
        }
        int byte = hr * 256 + 4 * l;
        byte ^= (hr & 7) << 4;
        *(ushort2*)((char*)qn_s + byte) = st;
    }
    __syncthreads();

    // ---- Phase B: QKVG MFMA.  waves 0-5: (tile, K/V); 6: Q t1; 7: G t1 ----
    {
        int t, isV = 0;
        const ushort* WT;
        if (wv < 6) { t = wv >> 1; isV = wv & 1; WT = isV ? wvT : wkT; }
        else        { t = 1; WT = (wv == 6) ? wqT : wgT; }
        const ushort* Wc = WT + (size_t)cl * DA;
        f32x4 acc[8] = {};
        #pragma unroll
        for (int ks = 0; ks < 4; ++ks) {
            int byteA = (t * 16 + cl) * 256 + (ks * 32 + ko) * 2;
            byteA ^= (cl & 7) << 4;
            bf16x8 a = *(const bf16x8*)((char*)qn_s + byteA);
            #pragma unroll
            for (int nf = 0; nf < 8; ++nf) {
                bf16x8 b = *(const bf16x8*)(Wc + (size_t)nf * 16 * DA + ks * 32 + ko);
                acc[nf] = __builtin_amdgcn_mfma_f32_16x16x32_bf16(a, b, acc[nf], 0, 0, 0);
            }
        }
        if (wv < 6) {
            float* dst = isV ? V_s : K_s;
            #pragma unroll
            for (int nf = 0; nf < 8; ++nf)
                #pragma unroll
                for (int r = 0; r < 4; ++r)
                    dst[(t * 16 + kq * 4 + r) * KSTR + nf * 16 + cl] = acc[nf][r];
        } else if (wv == 6) {
            #pragma unroll
            for (int nf = 0; nf < 8; ++nf)
                #pragma unroll
                for (int r = 0; r < 4; ++r)
                    Q_s[(kq * 4 + r) * KSTR + nf * 16 + cl] = acc[nf][r];
        } else {
            #pragma unroll
            for (int nf = 0; nf < 8; ++nf)
                #pragma unroll
                for (int r = 0; r < 4; ++r)
                    sG_s[(kq * 4 + r) * KSTR + nf * 16 + cl] = sigmoidf_(acc[nf][r]);
        }
    }
    __syncthreads();

    // ---- Phase C: banded attention (f32, LDS K/V) -> att_s ----
    {
        const int g = tid >> 3, l3 = tid & 7;
        const int rl = g >> 2, h = g & 3;
        const int gr = r0 + rl;
        const float scale = 0.17677669529663687f;   // 1/sqrt(32)
        float4 qr0 = *(const float4*)&Q_s[rl * KSTR + h * 32 + l3 * 4];
        const float* brow = band + ((size_t)gr * HH + h) * BAND;
        float s[BAND];
        float m = -1e30f;
        #pragma unroll
        for (int jo = 0; jo < BAND; ++jo) {
            int j = gr - WIN + jo;
            float sv = -1e30f;
            if ((unsigned)j < NA) {
                float4 kk = *(const float4*)&K_s[(rl + jo) * KSTR + h * 32 + l3 * 4];
                float d = 0.f;
                d = fmaf(qr0.x, kk.x, d); d = fmaf(qr0.y, kk.y, d);
                d = fmaf(qr0.z, kk.z, d); d = fmaf(qr0.w, kk.w, d);
                d += __shfl_xor(d, 1);
                d += __shfl_xor(d, 2);
                d += __shfl_xor(d, 4);
                sv = fmaf(d, scale, brow[jo]);
            }
            s[jo] = sv;
            m = fmaxf(m, sv);
        }
        float lsum = 0.f;
        #pragma unroll
        for (int jo = 0; jo < BAND; ++jo) {
            float p = __expf(s[jo] - m);
            s[jo] = p;
            lsum += p;
        }
        float inv = 1.0f / lsum;
        float4 o = {0.f, 0.f, 0.f, 0.f};
        #pragma unroll
        for (int jo = 0; jo < BAND; ++jo) {
            int j = gr - WIN + jo;
            if ((unsigned)j < NA) {
                float4 v = *(const float4*)&V_s[(rl + jo) * KSTR + h * 32 + l3 * 4];
                o.x = fmaf(s[jo], v.x, o.x);
                o.y = fmaf(s[jo], v.y, o.y);
                o.z = fmaf(s[jo], v.z, o.z);
                o.w = fmaf(s[jo], v.w, o.w);
            }
        }
        ushort4 st;
        st.x = f2bf(o.x * inv); st.y = f2bf(o.y * inv);
        st.z = f2bf(o.z * inv); st.w = f2bf(o.w * inv);
        int byte = rl * 256 + h * 64 + l3 * 8;
        byte ^= (rl & 7) << 4;
        *(ushort4*)((char*)att_s + byte) = st;
    }
    __syncthreads();

    // ---- Phase D: wo MFMA + gated residual -> q1_s ----
    {
        const int n0 = wv * 16;
        const ushort* Wc = woT + (size_t)(n0 + cl) * DA;
        f32x4 acc = {0.f, 0.f, 0.f, 0.f};
        #pragma unroll
        for (int ks = 0; ks < 4; ++ks) {
            int byteA = cl * 256 + (ks * 32 + ko) * 2;
            byteA ^= (cl & 7) << 4;
            bf16x8 a = *(const bf16x8*)((char*)att_s + byteA);
            bf16x8 b = *(const bf16x8*)(Wc + ks * 32 + ko);
            acc = __builtin_amdgcn_mfma_f32_16x16x32_bf16(a, b, acc, 0, 0, 0);
        }
        #pragma unroll
        for (int r = 0; r < 4; ++r) {
            int row = kq * 4 + r;
            int gr = r0 + row, col = n0 + cl;
            float qv = qg[(size_t)gr * DA + col];
            float sg = sG_s[row * KSTR + col];
            float g1v = gate1[(size_t)gr * DA + col];
            q1_s[row * KSTR + col] = (qv + sg * acc[r]) * (1.f + g1v);
        }
    }
    __syncthreads();

    // ---- Phase E: LN2 + modulate (in-reg, lane cl owns row cl) ----
    bf16x8 afr[4];
    {
        const int row = cl, gr = r0 + cl;
        float qv2[4][8];
        float sum = 0.f, sq = 0.f;
        #pragma unroll
        for (int ks = 0; ks < 4; ++ks) {
            float4 v0 = *(const float4*)&q1_s[row * KSTR + ks * 32 + ko];
            float4 v1 = *(const float4*)&q1_s[row * KSTR + ks * 32 + ko + 4];
            qv2[ks][0] = v0.x; qv2[ks][1] = v0.y; qv2[ks][2] = v0.z; qv2[ks][3] = v0.w;
            qv2[ks][4] = v1.x; qv2[ks][5] = v1.y; qv2[ks][6] = v1.z; qv2[ks][7] = v1.w;
            sum += v0.x + v0.y + v0.z + v0.w + v1.x + v1.y + v1.z + v1.w;
            sq += v0.x * v0.x + v0.y * v0.y + v0.z * v0.z + v0.w * v0.w
                + v1.x * v1.x + v1.y * v1.y + v1.z * v1.z + v1.w * v1.w;
        }
        sum += __shfl_xor(sum, 16); sq += __shfl_xor(sq, 16);
        sum += __shfl_xor(sum, 32); sq += __shfl_xor(sq, 32);
        float mean = sum * (1.0f / DA);
        float rs = rsqrtf(sq * (1.0f / DA) - mean * mean + 1e-5f);
        #pragma unroll
        for (int ks = 0; ks < 4; ++ks) {
            int k = ks * 32 + ko;
            float4 g0 = *(const float4*)&gb2[(size_t)gr * 256 + k];
            float4 g1v = *(const float4*)&gb2[(size_t)gr * 256 + k + 4];
            float4 b0 = *(const float4*)&gb2[(size_t)gr * 256 + 128 + k];
            float4 b1v = *(const float4*)&gb2[(size_t)gr * 256 + 128 + k + 4];
            float gg[8] = {g0.x, g0.y, g0.z, g0.w, g1v.x, g1v.y, g1v.z, g1v.w};
            float bb[8] = {b0.x, b0.y, b0.z, b0.w, b1v.x, b1v.y, b1v.z, b1v.w};
            #pragma unroll
            for (int j = 0; j < 8; ++j) {
                float xn = (qv2[ks][j] - mean) * rs;
                afr[ks][j] = (short)f2bf((1.f + gg[j]) * xn + bb[j]);
            }
        }
    }

    // ---- Phase F: sw1/sw3 MFMA -> hb_s; sw2 MFMA -> out ----
    {
        const int c0 = wv * 64;
        const ushort* W1 = s1T + (size_t)(c0 + cl) * DA;
        const ushort* W3 = s3T + (size_t)(c0 + cl) * DA;
        f32x4 acc1[4] = {}, acc3[4] = {};
        #pragma unroll
        for (int ks = 0; ks < 4; ++ks) {
            #pragma unroll
            for (int nf = 0; nf < 4; ++nf) {
                bf16x8 b1 = *(const bf16x8*)(W1 + (size_t)nf * 16 * DA + ks * 32 + ko);
                acc1[nf] = __builtin_amdgcn_mfma_f32_16x16x32_bf16(afr[ks], b1, acc1[nf], 0, 0, 0);
                bf16x8 b3 = *(const bf16x8*)(W3 + (size_t)nf * 16 * DA + ks * 32 + ko);
                acc3[nf] = __builtin_amdgcn_mfma_f32_16x16x32_bf16(afr[ks], b3, acc3[nf], 0, 0, 0);
            }
        }
        #pragma unroll
        for (int nf = 0; nf < 4; ++nf) {
            #pragma unroll
            for (int r = 0; r < 4; ++r) {
                float x1 = acc1[nf][r], x3 = acc3[nf][r];
                float h = x1 * sigmoidf_(x1) * x3;
                int rr = kq * 4 + r;
                int col = c0 + nf * 16 + cl;
                int byte = rr * 1024 + col * 2;
                byte ^= (rr & 7) << 4;
                *(ushort*)((char*)hb_s + byte) = f2bf(h);
            }
        }
    }
    __syncthreads();
    {
        const int n0 = wv * 16;
        const ushort* W2 = s2T + (size_t)(n0 + cl) * DF;
        f32x4 acc = {0.f, 0.f, 0.f, 0.f};
        #pragma unroll
        for (int ks = 0; ks < 16; ++ks) {
            int byteA = cl * 1024 + (ks * 32 + ko) * 2;
            byteA ^= (cl & 7) << 4;
            bf16x8 a = *(const bf16x8*)((char*)hb_s + byteA);
            bf16x8 b = *(const bf16x8*)(W2 + ks * 32 + ko);
            acc = __builtin_amdgcn_mfma_f32_16x16x32_bf16(a, b, acc, 0, 0, 0);
        }
        #pragma unroll
        for (int r = 0; r < 4; ++r) {
            int row = kq * 4 + r;
            int gr = r0 + row, col = n0 + cl;
            size_t rc = (size_t)gr * DA + col;
            out[rc] = q1_s[row * KSTR + col] + gate2[rc] * acc[r];
        }
    }
}

// ---------------------------------------------------------------------------
extern "C" void kernel_launch(void* const* d_in, const int* in_sizes, int n_in,
                              void* d_out, int out_size, void* d_ws, size_t ws_size,
                              hipStream_t stream)
{
    const float* q      = (const float*)d_in[0];
    const float* c_atom = (const float*)d_in[1];
    const float* h_cond = (const float*)d_in[2];
    const float* p_lm   = (const float*)d_in[3];
    const float* t_emb  = (const float*)d_in[4];
    const float* cond_w = (const float*)d_in[5];
    const float* cond_b = (const float*)d_in[6];
    const float* ad1w   = (const float*)d_in[7];
    const float* ad1b   = (const float*)d_in[8];
    const float* ad2w   = (const float*)d_in[9];
    const float* ad2b   = (const float*)d_in[10];
    const float* ln_g   = (const float*)d_in[11];
    const float* ln_b   = (const float*)d_in[12];
    const float* wq     = (const float*)d_in[13];
    const float* wk     = (const float*)d_in[14];
    const float* wv     = (const float*)d_in[15];
    const float* wg     = (const float*)d_in[16];
    const float* wo     = (const float*)d_in[17];
    const float* pair_w = (const float*)d_in[18];
    const float* pair_b = (const float*)d_in[19];
    const float* g1w    = (const float*)d_in[20];
    const float* g1b    = (const float*)d_in[21];
    const float* g2w    = (const float*)d_in[22];
    const float* g2b    = (const float*)d_in[23];
    const float* sw1    = (const float*)d_in[24];
    const float* sw3    = (const float*)d_in[25];
    const float* sw2    = (const float*)d_in[26];
    const int*   p_idx  = (const int*)d_in[27];
    const int*   tok    = (const int*)d_in[28];
    float* out = (float*)d_out;

    size_t off = 0;
    char* base = (char*)d_ws;
    auto alloc = [&](size_t bytes) -> void* {
        void* p = base + off;
        off += (bytes + 255) & ~(size_t)255;
        return p;
    };
    ushort* hcb     = (ushort*)alloc((size_t)NT * DM * 2);
    ushort* cab     = (ushort*)alloc((size_t)NA * DA * 2);
    ushort* cwT     = (ushort*)alloc((size_t)DM * DA * 2);
    ushort* a1T     = (ushort*)alloc((size_t)256 * 128 * 2);
    ushort* a2T     = (ushort*)alloc((size_t)256 * 128 * 2);
    ushort* wqT     = (ushort*)alloc((size_t)128 * 128 * 2);
    ushort* wkT     = (ushort*)alloc((size_t)128 * 128 * 2);
    ushort* wvT     = (ushort*)alloc((size_t)128 * 128 * 2);
    ushort* wgT     = (ushort*)alloc((size_t)128 * 128 * 2);
    ushort* woT     = (ushort*)alloc((size_t)128 * 128 * 2);
    ushort* g1T     = (ushort*)alloc((size_t)128 * 128 * 2);
    ushort* g2T     = (ushort*)alloc((size_t)128 * 128 * 2);
    ushort* s1T     = (ushort*)alloc((size_t)512 * 128 * 2);
    ushort* s3T     = (ushort*)alloc((size_t)512 * 128 * 2);
    ushort* s2T     = (ushort*)alloc((size_t)128 * 512 * 2);
    float*  gb1     = (float*)alloc((size_t)NA * 256 * 4);
    float*  gb2     = (float*)alloc((size_t)NA * 256 * 4);
    float*  gate1   = (float*)alloc((size_t)NA * DA * 4);
    float*  gate2   = (float*)alloc((size_t)NA * DA * 4);
    float*  band    = (float*)alloc((size_t)NA * HH * BAND * 4);

    k_prep<<<dim3(64, 16), 256, 0, stream>>>(
        h_cond, c_atom, cond_w, ad1w, ad2w, wq, wk, wv, wg, wo,
        g1w, g2w, sw1, sw3, sw2,
        hcb, cab, cwT, a1T, a2T, wqT, wkT, wvT, wgT, woT,
        g1T, g2T, s1T, s3T, s2T, band);
    k_condmod<<<384, 256, 0, stream>>>(
        hcb, tok, cwT, t_emb, cond_b, cab,
        a1T, a2T, g1T, g2T, ad1b, ad2b, g1b, g2b,
        p_lm, pair_w, pair_b, p_idx, band,
        gb1, gb2, gate1, gate2);
    k_mega<<<256, 512, 0, stream>>>(
        q, gb1, gb2, gate1, gate2, ln_g, ln_b, band,
        wqT, wkT, wvT, wgT, woT, s1T, s3T, s2T, out);
    (void)in_sizes; (void)n_in; (void)out_size; (void)ws_size;
}